// Round 5
// baseline (331.206 us; speedup 1.0000x reference)
//
#include <hip/hip_runtime.h>
#include <hip/hip_bf16.h>

#define N_VOX 120000
#define NTILES (N_VOX / 16)   // 7500

typedef __attribute__((ext_vector_type(8))) __bf16 bf16x8;
typedef __attribute__((ext_vector_type(4))) float floatx4;
using bf16 = __hip_bfloat16;

__device__ __forceinline__ float b2f(bf16 v) { return __bfloat162float(v); }
__device__ __forceinline__ bf16 f2b(float v) { return __float2bfloat16(v); }

// All VMEM in the conv K-loop is inline asm: (a) compiler cannot sink/split
// the batched gathers, (b) vmcnt bookkeeping is deterministic, enabling
// cross-tile prefetch with exact s_waitcnt immediates.
__device__ __forceinline__ bf16x8 gload16(const bf16* p) {
    bf16x8 r;
    asm volatile("global_load_dwordx4 %0, %1, off" : "=v"(r) : "v"(p));
    return r;
}
__device__ __forceinline__ int gloadi(const int* p) {
    int r;
    asm volatile("global_load_dword %0, %1, off" : "=v"(r) : "v"(p));
    return r;
}
__device__ __forceinline__ void gstore16(bf16* p, bf16x8 v) {
    asm volatile("global_store_dwordx4 %0, %1, off" :: "v"(p), "v"(v) : "memory");
}
__device__ __forceinline__ void vm_wait0() { asm volatile("s_waitcnt vmcnt(0)" ::: "memory"); }
__device__ __forceinline__ void vm_wait1() { asm volatile("s_waitcnt vmcnt(1)" ::: "memory"); }
__device__ __forceinline__ void vm_wait2() { asm volatile("s_waitcnt vmcnt(2)" ::: "memory"); }
__device__ __forceinline__ void vm_wait3() { asm volatile("s_waitcnt vmcnt(3)" ::: "memory"); }
__device__ __forceinline__ void pin(bf16x8& x) { asm volatile("" : "+v"(x)); }
__device__ __forceinline__ void pini(int& x)   { asm volatile("" : "+v"(x)); }

// ---------------------------------------------------------------------------
// Gather-GEMM conv: tout[n,:] = lrelu( sum_k uin[nbr[n,k],:] @ W[k] )
// One wave per 16-row tile, all COUT cols; grid-stride; no in-loop barriers.
// BASELINE choreography (proven): all gathers unconditional; idx loads
// coalesced via LDS (prefetched 1 tile ahead); C-tile transposed through
// wave-private LDS -> coalesced dwordx4 stores.
// R4 change: conv<64,64> runs NW=16 (1024-thr blocks). LDS 129 KB still fits
// one block/CU, but waves/SIMD go 2 -> 4, doubling TLP for gather-latency
// hiding on the two heaviest dispatches. No instruction-level changes.
// ---------------------------------------------------------------------------
template<int CIN, int COUT, int NW, bool STATS>
__global__ __launch_bounds__(NW * 64) void conv_kernel(
    const bf16* __restrict__ uin,     // [N_VOX+1, CIN], pad row zero
    const int*  __restrict__ nbr,     // [N_VOX, 9]
    const bf16* __restrict__ bpack,   // prepacked B frags
    bf16* __restrict__ tout,          // [N_VOX, COUT]
    float* __restrict__ stats)        // [sum[64], sumsq[64]]
{
    constexpr int NT = COUT / 16;
    constexpr int K = 9 * CIN;
    constexpr int KSTEPS = (K + 31) / 32;
    constexpr bool BLDS = (COUT == 64);
    constexpr int NFRAG = KSTEPS * NT;
    constexpr int NSTORE = (16 * COUT) / 512;   // 1 (COUT=32) or 2 (COUT=64)

    __shared__ bf16x8 Bs[BLDS ? NFRAG * 64 : 1];
    __shared__ int idxb[NW][2][192];
    __shared__ __align__(16) bf16 tbuf[NW][16 * COUT];
    __shared__ float sS[64], sS2[64];

    const int lane = threadIdx.x & 63;
    const int wave = threadIdx.x >> 6;
    const int m    = lane & 15;
    const int quad = lane >> 4;

    if (STATS && threadIdx.x < 64) { sS[threadIdx.x] = 0.f; sS2[threadIdx.x] = 0.f; }

    const bf16x8* bp = reinterpret_cast<const bf16x8*>(bpack);
    bf16x8 Bf[BLDS ? 1 : NFRAG];
    if constexpr (BLDS) {
        for (int f = threadIdx.x; f < NFRAG * 64; f += NW * 64) Bs[f] = bp[f];
    } else {
#pragma unroll
        for (int f = 0; f < NFRAG; ++f) Bf[f] = bp[f * 64 + lane];
    }
    __syncthreads();

    float ssum[NT], ssum2[NT];
#pragma unroll
    for (int c = 0; c < NT; ++c) { ssum[c] = 0.f; ssum2[c] = 0.f; }

    const int STRIDE = gridDim.x * NW;
    const int t0 = blockIdx.x * NW + wave;      // < NTILES by grid construction

    // Prologue: coalesced idx load for tile t0 (144 contiguous dwords).
    {
        const int* b0 = nbr + t0 * 144;
        int i0 = gloadi(b0 + lane);
        int i1 = gloadi(b0 + 64 + lane);
        int i2 = gloadi(b0 + 128 + (lane & 15));
        vm_wait0();
        pini(i0); pini(i1); pini(i2);
        int* ib = idxb[wave][0];
        ib[lane] = i0; ib[64 + lane] = i1; ib[128 + (lane & 15)] = i2;
    }

    int p = 0;
    for (int tile = t0; tile < NTILES; tile += STRIDE) {
        // 1) per-lane idx from LDS (no TA traffic)
        const int* ib = idxb[wave][p];
        int idx[9];
#pragma unroll
        for (int nb = 0; nb < 9; ++nb) idx[nb] = ib[m * 9 + nb];

        // 2) issue all K-panel gathers (asm, batched)
        bf16x8 a[KSTEPS];
#pragma unroll
        for (int t = 0; t < KSTEPS; ++t) {
            const bf16* src;
            if constexpr (CIN == 64) {
                src = uin + (((size_t)idx[t >> 1]) << 6) + ((t & 1) << 5) + quad * 8;
            } else if constexpr (CIN == 32) {
                src = uin + (((size_t)idx[t]) << 5) + quad * 8;
            } else {  // CIN == 16
                constexpr int KS = 9 * 16;
                const int j1 = (2 * t + 1 > 8) ? 8 : 2 * t + 1;
                int r_ = (quad & 2) ? idx[j1] : idx[2 * t];
                if (t * 32 + 24 >= KS) {
                    if (t * 32 + quad * 8 >= KS) r_ = N_VOX;  // tail -> pad row
                }
                src = uin + (((size_t)r_) << 4) + ((quad & 1) << 3);
            }
            a[t] = gload16(src);
        }

        // 3) prefetch next tile's idx (coalesced, stays in flight across MFMA)
        const int tnext = (tile + STRIDE < NTILES) ? tile + STRIDE : tile;
        const int* bn_ = nbr + tnext * 144;
        int i0 = gloadi(bn_ + lane);
        int i1 = gloadi(bn_ + 64 + lane);
        int i2 = gloadi(bn_ + 128 + (lane & 15));

        // 4) wait gathers (3 idx loads remain in flight), compute
        vm_wait3();
#pragma unroll
        for (int t = 0; t < KSTEPS; ++t) pin(a[t]);

        floatx4 acc[NT];
#pragma unroll
        for (int c = 0; c < NT; ++c) acc[c] = (floatx4){0.f, 0.f, 0.f, 0.f};
#pragma unroll
        for (int t = 0; t < KSTEPS; ++t) {
#pragma unroll
            for (int c = 0; c < NT; ++c) {
                const bf16x8 b = BLDS ? Bs[(t * NT + c) * 64 + lane] : Bf[t * NT + c];
                acc[c] = __builtin_amdgcn_mfma_f32_16x16x32_bf16(a[t], b, acc[c], 0, 0, 0);
            }
        }

        // 5) epilogue: lrelu + stats + LDS transpose + coalesced stores
        bf16* tb = tbuf[wave];
#pragma unroll
        for (int c = 0; c < NT; ++c) {
            float ps = 0.f, ps2 = 0.f;
#pragma unroll
            for (int i = 0; i < 4; ++i) {
                float v = acc[c][i];
                v = v > 0.f ? v : 0.01f * v;
                tb[(quad * 4 + i) * COUT + c * 16 + m] = f2b(v);
                ps += v; ps2 += v * v;
            }
            ssum[c] += ps; ssum2[c] += ps2;
        }
#pragma unroll
        for (int g = 0; g < NSTORE; ++g) {
            const int off = g * 512 + lane * 8;
            bf16x8 row = *reinterpret_cast<const bf16x8*>(tb + off);
            gstore16(tout + (size_t)tile * (16 * COUT) + off, row);
        }

        // 6) idx arrived (NSTORE stores still in flight); stash for next iter
        if constexpr (NSTORE == 2) vm_wait2(); else vm_wait1();
        pini(i0); pini(i1); pini(i2);
        int* ibn = idxb[wave][p ^ 1];
        ibn[lane] = i0; ibn[64 + lane] = i1; ibn[128 + (lane & 15)] = i2;
        p ^= 1;
    }

    if constexpr (STATS) {
#pragma unroll
        for (int c = 0; c < NT; ++c) {
            atomicAdd(&sS[c * 16 + m], ssum[c]);
            atomicAdd(&sS2[c * 16 + m], ssum2[c]);
        }
        __syncthreads();
        if (threadIdx.x < COUT) {
            atomicAdd(&stats[threadIdx.x],      sS[threadIdx.x]);
            atomicAdd(&stats[64 + threadIdx.x], sS2[threadIdx.x]);
        }
    }
}

// ---------------------------------------------------------------------------
// In-place BN affine on t[N_VOX,C] (bf16) + zero pad row.
// ---------------------------------------------------------------------------
template<int C>
__global__ __launch_bounds__(256) void bnapply_kernel(
    bf16* t, const float* __restrict__ s,
    const float* __restrict__ g, const float* __restrict__ b)
{
    __shared__ float pa[64], pc[64];
    if (threadIdx.x < C) {
        const float inv_n = 1.0f / N_VOX;
        const float mu = s[threadIdx.x] * inv_n;
        const float var = fmaxf(s[64 + threadIdx.x] * inv_n - mu * mu, 0.f);
        const float a = rsqrtf(var + 1e-5f) * g[threadIdx.x];
        pa[threadIdx.x] = a;
        pc[threadIdx.x] = b[threadIdx.x] - mu * a;
    }
    __syncthreads();
    const int i8 = (blockIdx.x * 256 + threadIdx.x) * 8;
    if (i8 >= (N_VOX + 1) * C) return;
    if (i8 >= N_VOX * C) {
        uint4 z = {0, 0, 0, 0};
        *reinterpret_cast<uint4*>(t + i8) = z;
        return;
    }
    union { bf16x8 v; bf16 e[8]; } U, O;
    U.v = *reinterpret_cast<const bf16x8*>(t + i8);
    const int ch0 = i8 & (C - 1);
#pragma unroll
    for (int j = 0; j < 8; ++j)
        O.e[j] = f2b(pa[ch0 + j] * b2f(U.e[j]) + pc[ch0 + j]);
    *reinterpret_cast<bf16x8*>(t + i8) = O.v;
}

// ---------------------------------------------------------------------------
// out = BN_a(ta) + BN_b(tb); OUT bf16 (+pad row) or float (final).
// ---------------------------------------------------------------------------
template<int C, bool ZROW, typename OUT>
__global__ __launch_bounds__(256) void addbn_kernel(
    const bf16* ta, const float* __restrict__ sa,
    const float* __restrict__ ga, const float* __restrict__ ba,
    const bf16* tb, const float* __restrict__ sb,
    const float* __restrict__ gb, const float* __restrict__ bb,
    OUT* out)
{
    __shared__ float paa[64], pca[64], pab[64], pcb[64];
    if (threadIdx.x < C) {
        const float inv_n = 1.0f / N_VOX;
        const float ma = sa[threadIdx.x] * inv_n;
        const float va = fmaxf(sa[64 + threadIdx.x] * inv_n - ma * ma, 0.f);
        const float aa = rsqrtf(va + 1e-5f) * ga[threadIdx.x];
        paa[threadIdx.x] = aa;
        pca[threadIdx.x] = ba[threadIdx.x] - ma * aa;
        const float mb = sb[threadIdx.x] * inv_n;
        const float vb = fmaxf(sb[64 + threadIdx.x] * inv_n - mb * mb, 0.f);
        const float ab = rsqrtf(vb + 1e-5f) * gb[threadIdx.x];
        pab[threadIdx.x] = ab;
        pcb[threadIdx.x] = bb[threadIdx.x] - mb * ab;
    }
    __syncthreads();
    constexpr int TOTAL = (N_VOX + (ZROW ? 1 : 0)) * C;
    const int i8 = (blockIdx.x * 256 + threadIdx.x) * 8;
    if (i8 >= TOTAL) return;
    if (ZROW && i8 >= N_VOX * C) {
        uint4 z = {0, 0, 0, 0};
        *reinterpret_cast<uint4*>((bf16*)out + i8) = z;
        return;
    }
    union { bf16x8 v; bf16 e[8]; } A, B;
    A.v = *reinterpret_cast<const bf16x8*>(ta + i8);
    B.v = *reinterpret_cast<const bf16x8*>(tb + i8);
    const int ch0 = i8 & (C - 1);
    float r[8];
#pragma unroll
    for (int j = 0; j < 8; ++j)
        r[j] = paa[ch0 + j] * b2f(A.e[j]) + pca[ch0 + j]
             + pab[ch0 + j] * b2f(B.e[j]) + pcb[ch0 + j];
    if constexpr (sizeof(OUT) == 2) {
        union { bf16x8 v; bf16 e[8]; } O;
#pragma unroll
        for (int j = 0; j < 8; ++j) O.e[j] = f2b(r[j]);
        *reinterpret_cast<bf16x8*>(out + i8) = O.v;
    } else {
#pragma unroll
        for (int j = 0; j < 8; ++j) out[i8 + j] = r[j];
    }
}

// ---------------------------------------------------------------------------
// Prep: u0 = bf16(x) + zero pad row; pack 8 f32 weights into bf16 MFMA
// B-fragment order; zero stats; zero pad row of u3.
// ---------------------------------------------------------------------------
#define PACK_TOTAL 139264
__global__ __launch_bounds__(256) void prep_kernel(
    const float* __restrict__ x,
    const float* W0, const float* W1, const float* W2, const float* W3,
    const float* W4, const float* W5, const float* W6, const float* W7,
    bf16* __restrict__ u0, bf16* __restrict__ bpack,
    float* __restrict__ stats, bf16* __restrict__ u3)
{
    const int gid = blockIdx.x * 256 + threadIdx.x;
    constexpr int NXE = (N_VOX + 1) * 16;
    if (gid < NXE) {
        u0[gid] = (gid < N_VOX * 16) ? f2b(x[gid]) : f2b(0.f);
        return;
    }
    int p = gid - NXE;
    if (p < PACK_TOTAL) {
        constexpr int cin[8]  = {16, 32, 16, 32, 32, 64, 32, 64};
        constexpr int cout[8] = {32, 32, 32, 32, 64, 64, 64, 64};
        constexpr int offs[9] = {0, 5120, 14336, 19456, 28672, 47104, 83968, 102400, 139264};
        const float* Ws[8] = {W0, W1, W2, W3, W4, W5, W6, W7};
        int w = 0;
        while (p >= offs[w + 1]) ++w;
        const int e = p - offs[w];
        const int CI = cin[w], CO = cout[w];
        const int NTl = CO / 16;
        const int j = e & 7;
        const int lane = (e >> 3) & 63;
        const int rest = e >> 9;
        const int c = rest % NTl;
        const int t = rest / NTl;
        const int ncol = c * 16 + (lane & 15);
        const int k = t * 32 + (lane >> 4) * 8 + j;
        float val = 0.f;
        if (k < 9 * CI) {
            const int nbq = k / CI;
            const int ci = k % CI;
            val = Ws[w][(nbq * CI + ci) * CO + ncol];
        }
        bpack[p] = f2b(val);
        return;
    }
    p -= PACK_TOTAL;
    if (p < 1024) { stats[p] = 0.f; return; }
    p -= 1024;
    if (p < 32) u3[N_VOX * 32 + p] = f2b(0.f);
}

extern "C" void kernel_launch(void* const* d_in, const int* in_sizes, int n_in,
                              void* d_out, int out_size, void* d_ws, size_t ws_size,
                              hipStream_t stream) {
    const float* x     = (const float*)d_in[0];
    const int* nbr133  = (const int*)d_in[1];
    const int* nbr313  = (const int*)d_in[2];
    const float* W_c1  = (const float*)d_in[3];
    const float* g0    = (const float*)d_in[4];
    const float* b0    = (const float*)d_in[5];
    const float* W_c12 = (const float*)d_in[6];
    const float* g02   = (const float*)d_in[7];
    const float* b02   = (const float*)d_in[8];
    const float* W_c2  = (const float*)d_in[9];
    const float* W_c3  = (const float*)d_in[10];
    const float* g2    = (const float*)d_in[11];
    const float* b2    = (const float*)d_in[12];
    const float* W_r1  = (const float*)d_in[13];
    const float* rg0   = (const float*)d_in[14];
    const float* rb0   = (const float*)d_in[15];
    const float* W_r12 = (const float*)d_in[16];
    const float* rg02  = (const float*)d_in[17];
    const float* rb02  = (const float*)d_in[18];
    const float* W_r2  = (const float*)d_in[19];
    const float* rg1   = (const float*)d_in[20];
    const float* rb1   = (const float*)d_in[21];
    const float* W_r3  = (const float*)d_in[22];
    const float* rg2   = (const float*)d_in[23];
    const float* rb2   = (const float*)d_in[24];

    // Workspace aliasing schedule identical to R3/R5/R6 (correctness-proven).
    char* ws = (char*)d_ws;
    size_t off = 0;
    auto alloc = [&](size_t bytes) -> char* {
        off = (off + 255) & ~(size_t)255;
        char* p = ws + off;
        off += bytes;
        return p;
    };
    const size_t NV = N_VOX;
    bf16* u0   = (bf16*)alloc((NV + 1) * 16 * 2);
    bf16* B1u3 = (bf16*)alloc((NV + 1) * 32 * 2);
    bf16* T4   = (bf16*)alloc(NV * 32 * 2);
    bf16* T2uy = (bf16*)alloc((NV + 1) * 32 * 2);
    bf16* B5B7 = (bf16*)alloc((NV + 1) * 64 * 2);
    bf16* T8   = (bf16*)alloc(NV * 64 * 2);
    bf16* bpack = (bf16*)alloc((size_t)PACK_TOTAL * 2);
    float* stats = (float*)alloc(1024 * 4);
    bf16* T6 = (bf16*)ws;    // alias R0..R2 (19.2 MB available >= 15.36 MB)

    float* st1 = stats + 0 * 128;
    float* st2 = stats + 1 * 128;
    float* st4 = stats + 3 * 128;
    float* st5 = stats + 4 * 128;
    float* st6 = stats + 5 * 128;
    float* st7 = stats + 6 * 128;
    float* st8 = stats + 7 * 128;

    bf16* bp0 = bpack + 0;       // W_c1  (16->32)
    bf16* bp1 = bpack + 5120;    // W_c12 (32->32)
    bf16* bp2 = bpack + 14336;   // W_c2  (16->32)
    bf16* bp3 = bpack + 19456;   // W_c3  (32->32)
    bf16* bp4 = bpack + 28672;   // W_r1  (32->64)
    bf16* bp5 = bpack + 47104;   // W_r12 (64->64)
    bf16* bp6 = bpack + 83968;   // W_r2  (32->64)
    bf16* bp7 = bpack + 102400;  // W_r3  (64->64)

    const int prep_total = (N_VOX + 1) * 16 + PACK_TOTAL + 1024 + 32;
    prep_kernel<<<(prep_total + 255) / 256, 256, 0, stream>>>(
        x, W_c1, W_c12, W_c2, W_c3, W_r1, W_r12, W_r2, W_r3, u0, bpack, stats, B1u3);

    const int E32 = (((N_VOX + 1) * 32) / 8 + 255) / 256;
    const int E64 = (((N_VOX + 1) * 64) / 8 + 255) / 256;

    // ResContextBlock
    conv_kernel<16, 32, 4, true><<<768, 256, 0, stream>>>(u0, nbr133, bp0, B1u3, st1);
    bnapply_kernel<32><<<E32, 256, 0, stream>>>(B1u3, st1, g0, b0);
    conv_kernel<32, 32, 4, true><<<768, 256, 0, stream>>>(B1u3, nbr313, bp1, T2uy, st2);
    conv_kernel<16, 32, 4, false><<<768, 256, 0, stream>>>(u0, nbr313, bp2, B1u3, nullptr);
    conv_kernel<32, 32, 4, true><<<768, 256, 0, stream>>>(B1u3, nbr133, bp3, T4, st4);
    addbn_kernel<32, true, bf16><<<E32, 256, 0, stream>>>(
        T2uy, st2, g02, b02, T4, st4, g2, b2, T2uy);
    // ResBlock
    conv_kernel<32, 64, 8, true><<<512, 512, 0, stream>>>(T2uy, nbr313, bp4, B5B7, st5);
    bnapply_kernel<64><<<E64, 256, 0, stream>>>(B5B7, st5, rg0, rb0);
    conv_kernel<64, 64, 16, true><<<128, 1024, 0, stream>>>(B5B7, nbr133, bp5, T6, st6);
    conv_kernel<32, 64, 8, true><<<512, 512, 0, stream>>>(T2uy, nbr133, bp6, B5B7, st7);
    bnapply_kernel<64><<<E64, 256, 0, stream>>>(B5B7, st7, rg1, rb1);
    conv_kernel<64, 64, 16, true><<<128, 1024, 0, stream>>>(B5B7, nbr313, bp7, T8, st8);
    addbn_kernel<64, false, float><<<((N_VOX * 64 / 8) + 255) / 256, 256, 0, stream>>>(
        T6, st6, rg02, rb02, T8, st8, rg2, rb2, (float*)d_out);
}

// Round 6
// 323.726 us; speedup vs baseline: 1.0231x; 1.0231x over previous
//
#include <hip/hip_runtime.h>
#include <hip/hip_bf16.h>

#define N_VOX 120000
#define NTILES (N_VOX / 16)   // 7500

typedef __attribute__((ext_vector_type(8))) __bf16 bf16x8;
typedef __attribute__((ext_vector_type(4))) float floatx4;
using bf16 = __hip_bfloat16;

__device__ __forceinline__ float b2f(bf16 v) { return __bfloat162float(v); }
__device__ __forceinline__ bf16 f2b(float v) { return __float2bfloat16(v); }

// All VMEM in the conv K-loop is inline asm: (a) compiler cannot sink/split
// the batched gathers, (b) vmcnt bookkeeping is deterministic, enabling
// cross-tile prefetch with exact s_waitcnt immediates.
__device__ __forceinline__ bf16x8 gload16(const bf16* p) {
    bf16x8 r;
    asm volatile("global_load_dwordx4 %0, %1, off" : "=v"(r) : "v"(p));
    return r;
}
__device__ __forceinline__ int gloadi(const int* p) {
    int r;
    asm volatile("global_load_dword %0, %1, off" : "=v"(r) : "v"(p));
    return r;
}
__device__ __forceinline__ void gstore16(bf16* p, bf16x8 v) {
    asm volatile("global_store_dwordx4 %0, %1, off" :: "v"(p), "v"(v) : "memory");
}
__device__ __forceinline__ void vm_wait0() { asm volatile("s_waitcnt vmcnt(0)" ::: "memory"); }
__device__ __forceinline__ void vm_wait1() { asm volatile("s_waitcnt vmcnt(1)" ::: "memory"); }
__device__ __forceinline__ void vm_wait2() { asm volatile("s_waitcnt vmcnt(2)" ::: "memory"); }
__device__ __forceinline__ void vm_wait3() { asm volatile("s_waitcnt vmcnt(3)" ::: "memory"); }
__device__ __forceinline__ void pin(bf16x8& x) { asm volatile("" : "+v"(x)); }
__device__ __forceinline__ void pini(int& x)   { asm volatile("" : "+v"(x)); }

// ---------------------------------------------------------------------------
// Gather-GEMM conv: tout[n,:] = lrelu( sum_k uin[nbr[n,k],:] @ W[k] )
// One wave per 16-row tile, all COUT cols; grid-stride; no in-loop barriers.
// BASELINE choreography (proven): all gathers unconditional; idx loads
// coalesced via LDS (prefetched 1 tile ahead); C-tile transposed through
// wave-private LDS -> coalesced dwordx4 stores.
// R5: conv<64,64> runs NW=16 with grid=256 (R4's grid=128 used only half
// the CUs). 128.5 KB LDS -> 1 block/CU on ALL 256 CUs, 16 waves/CU =
// 4 waves/SIMD, 2x the baseline TLP for gather-latency hiding.
// ---------------------------------------------------------------------------
template<int CIN, int COUT, int NW, bool STATS>
__global__ __launch_bounds__(NW * 64) void conv_kernel(
    const bf16* __restrict__ uin,     // [N_VOX+1, CIN], pad row zero
    const int*  __restrict__ nbr,     // [N_VOX, 9]
    const bf16* __restrict__ bpack,   // prepacked B frags
    bf16* __restrict__ tout,          // [N_VOX, COUT]
    float* __restrict__ stats)        // [sum[64], sumsq[64]]
{
    constexpr int NT = COUT / 16;
    constexpr int K = 9 * CIN;
    constexpr int KSTEPS = (K + 31) / 32;
    constexpr bool BLDS = (COUT == 64);
    constexpr int NFRAG = KSTEPS * NT;
    constexpr int NSTORE = (16 * COUT) / 512;   // 1 (COUT=32) or 2 (COUT=64)

    __shared__ bf16x8 Bs[BLDS ? NFRAG * 64 : 1];
    __shared__ int idxb[NW][2][192];
    __shared__ __align__(16) bf16 tbuf[NW][16 * COUT];
    __shared__ float sS[64], sS2[64];

    const int lane = threadIdx.x & 63;
    const int wave = threadIdx.x >> 6;
    const int m    = lane & 15;
    const int quad = lane >> 4;

    if (STATS && threadIdx.x < 64) { sS[threadIdx.x] = 0.f; sS2[threadIdx.x] = 0.f; }

    const bf16x8* bp = reinterpret_cast<const bf16x8*>(bpack);
    bf16x8 Bf[BLDS ? 1 : NFRAG];
    if constexpr (BLDS) {
        for (int f = threadIdx.x; f < NFRAG * 64; f += NW * 64) Bs[f] = bp[f];
    } else {
#pragma unroll
        for (int f = 0; f < NFRAG; ++f) Bf[f] = bp[f * 64 + lane];
    }
    __syncthreads();

    float ssum[NT], ssum2[NT];
#pragma unroll
    for (int c = 0; c < NT; ++c) { ssum[c] = 0.f; ssum2[c] = 0.f; }

    const int STRIDE = gridDim.x * NW;
    const int t0 = blockIdx.x * NW + wave;      // < NTILES by grid construction

    // Prologue: coalesced idx load for tile t0 (144 contiguous dwords).
    {
        const int* b0 = nbr + t0 * 144;
        int i0 = gloadi(b0 + lane);
        int i1 = gloadi(b0 + 64 + lane);
        int i2 = gloadi(b0 + 128 + (lane & 15));
        vm_wait0();
        pini(i0); pini(i1); pini(i2);
        int* ib = idxb[wave][0];
        ib[lane] = i0; ib[64 + lane] = i1; ib[128 + (lane & 15)] = i2;
    }

    int p = 0;
    for (int tile = t0; tile < NTILES; tile += STRIDE) {
        // 1) per-lane idx from LDS (no TA traffic)
        const int* ib = idxb[wave][p];
        int idx[9];
#pragma unroll
        for (int nb = 0; nb < 9; ++nb) idx[nb] = ib[m * 9 + nb];

        // 2) issue all K-panel gathers (asm, batched)
        bf16x8 a[KSTEPS];
#pragma unroll
        for (int t = 0; t < KSTEPS; ++t) {
            const bf16* src;
            if constexpr (CIN == 64) {
                src = uin + (((size_t)idx[t >> 1]) << 6) + ((t & 1) << 5) + quad * 8;
            } else if constexpr (CIN == 32) {
                src = uin + (((size_t)idx[t]) << 5) + quad * 8;
            } else {  // CIN == 16
                constexpr int KS = 9 * 16;
                const int j1 = (2 * t + 1 > 8) ? 8 : 2 * t + 1;
                int r_ = (quad & 2) ? idx[j1] : idx[2 * t];
                if (t * 32 + 24 >= KS) {
                    if (t * 32 + quad * 8 >= KS) r_ = N_VOX;  // tail -> pad row
                }
                src = uin + (((size_t)r_) << 4) + ((quad & 1) << 3);
            }
            a[t] = gload16(src);
        }

        // 3) prefetch next tile's idx (coalesced, stays in flight across MFMA)
        const int tnext = (tile + STRIDE < NTILES) ? tile + STRIDE : tile;
        const int* bn_ = nbr + tnext * 144;
        int i0 = gloadi(bn_ + lane);
        int i1 = gloadi(bn_ + 64 + lane);
        int i2 = gloadi(bn_ + 128 + (lane & 15));

        // 4) wait gathers (3 idx loads remain in flight), compute
        vm_wait3();
#pragma unroll
        for (int t = 0; t < KSTEPS; ++t) pin(a[t]);

        floatx4 acc[NT];
#pragma unroll
        for (int c = 0; c < NT; ++c) acc[c] = (floatx4){0.f, 0.f, 0.f, 0.f};
#pragma unroll
        for (int t = 0; t < KSTEPS; ++t) {
#pragma unroll
            for (int c = 0; c < NT; ++c) {
                const bf16x8 b = BLDS ? Bs[(t * NT + c) * 64 + lane] : Bf[t * NT + c];
                acc[c] = __builtin_amdgcn_mfma_f32_16x16x32_bf16(a[t], b, acc[c], 0, 0, 0);
            }
        }

        // 5) epilogue: lrelu + stats + LDS transpose + coalesced stores
        bf16* tb = tbuf[wave];
#pragma unroll
        for (int c = 0; c < NT; ++c) {
            float ps = 0.f, ps2 = 0.f;
#pragma unroll
            for (int i = 0; i < 4; ++i) {
                float v = acc[c][i];
                v = v > 0.f ? v : 0.01f * v;
                tb[(quad * 4 + i) * COUT + c * 16 + m] = f2b(v);
                ps += v; ps2 += v * v;
            }
            ssum[c] += ps; ssum2[c] += ps2;
        }
#pragma unroll
        for (int g = 0; g < NSTORE; ++g) {
            const int off = g * 512 + lane * 8;
            bf16x8 row = *reinterpret_cast<const bf16x8*>(tb + off);
            gstore16(tout + (size_t)tile * (16 * COUT) + off, row);
        }

        // 6) idx arrived (NSTORE stores still in flight); stash for next iter
        if constexpr (NSTORE == 2) vm_wait2(); else vm_wait1();
        pini(i0); pini(i1); pini(i2);
        int* ibn = idxb[wave][p ^ 1];
        ibn[lane] = i0; ibn[64 + lane] = i1; ibn[128 + (lane & 15)] = i2;
        p ^= 1;
    }

    if constexpr (STATS) {
#pragma unroll
        for (int c = 0; c < NT; ++c) {
            atomicAdd(&sS[c * 16 + m], ssum[c]);
            atomicAdd(&sS2[c * 16 + m], ssum2[c]);
        }
        __syncthreads();
        if (threadIdx.x < COUT) {
            atomicAdd(&stats[threadIdx.x],      sS[threadIdx.x]);
            atomicAdd(&stats[64 + threadIdx.x], sS2[threadIdx.x]);
        }
    }
}

// ---------------------------------------------------------------------------
// In-place BN affine on t[N_VOX,C] (bf16) + zero pad row.
// ---------------------------------------------------------------------------
template<int C>
__global__ __launch_bounds__(256) void bnapply_kernel(
    bf16* t, const float* __restrict__ s,
    const float* __restrict__ g, const float* __restrict__ b)
{
    __shared__ float pa[64], pc[64];
    if (threadIdx.x < C) {
        const float inv_n = 1.0f / N_VOX;
        const float mu = s[threadIdx.x] * inv_n;
        const float var = fmaxf(s[64 + threadIdx.x] * inv_n - mu * mu, 0.f);
        const float a = rsqrtf(var + 1e-5f) * g[threadIdx.x];
        pa[threadIdx.x] = a;
        pc[threadIdx.x] = b[threadIdx.x] - mu * a;
    }
    __syncthreads();
    const int i8 = (blockIdx.x * 256 + threadIdx.x) * 8;
    if (i8 >= (N_VOX + 1) * C) return;
    if (i8 >= N_VOX * C) {
        uint4 z = {0, 0, 0, 0};
        *reinterpret_cast<uint4*>(t + i8) = z;
        return;
    }
    union { bf16x8 v; bf16 e[8]; } U, O;
    U.v = *reinterpret_cast<const bf16x8*>(t + i8);
    const int ch0 = i8 & (C - 1);
#pragma unroll
    for (int j = 0; j < 8; ++j)
        O.e[j] = f2b(pa[ch0 + j] * b2f(U.e[j]) + pc[ch0 + j]);
    *reinterpret_cast<bf16x8*>(t + i8) = O.v;
}

// ---------------------------------------------------------------------------
// out = BN_a(ta) + BN_b(tb); OUT bf16 (+pad row) or float (final).
// ---------------------------------------------------------------------------
template<int C, bool ZROW, typename OUT>
__global__ __launch_bounds__(256) void addbn_kernel(
    const bf16* ta, const float* __restrict__ sa,
    const float* __restrict__ ga, const float* __restrict__ ba,
    const bf16* tb, const float* __restrict__ sb,
    const float* __restrict__ gb, const float* __restrict__ bb,
    OUT* out)
{
    __shared__ float paa[64], pca[64], pab[64], pcb[64];
    if (threadIdx.x < C) {
        const float inv_n = 1.0f / N_VOX;
        const float ma = sa[threadIdx.x] * inv_n;
        const float va = fmaxf(sa[64 + threadIdx.x] * inv_n - ma * ma, 0.f);
        const float aa = rsqrtf(va + 1e-5f) * ga[threadIdx.x];
        paa[threadIdx.x] = aa;
        pca[threadIdx.x] = ba[threadIdx.x] - ma * aa;
        const float mb = sb[threadIdx.x] * inv_n;
        const float vb = fmaxf(sb[64 + threadIdx.x] * inv_n - mb * mb, 0.f);
        const float ab = rsqrtf(vb + 1e-5f) * gb[threadIdx.x];
        pab[threadIdx.x] = ab;
        pcb[threadIdx.x] = bb[threadIdx.x] - mb * ab;
    }
    __syncthreads();
    constexpr int TOTAL = (N_VOX + (ZROW ? 1 : 0)) * C;
    const int i8 = (blockIdx.x * 256 + threadIdx.x) * 8;
    if (i8 >= TOTAL) return;
    if (ZROW && i8 >= N_VOX * C) {
        uint4 z = {0, 0, 0, 0};
        *reinterpret_cast<uint4*>((bf16*)out + i8) = z;
        return;
    }
    union { bf16x8 v; bf16 e[8]; } A, B;
    A.v = *reinterpret_cast<const bf16x8*>(ta + i8);
    B.v = *reinterpret_cast<const bf16x8*>(tb + i8);
    const int ch0 = i8 & (C - 1);
    float r[8];
#pragma unroll
    for (int j = 0; j < 8; ++j)
        r[j] = paa[ch0 + j] * b2f(A.e[j]) + pca[ch0 + j]
             + pab[ch0 + j] * b2f(B.e[j]) + pcb[ch0 + j];
    if constexpr (sizeof(OUT) == 2) {
        union { bf16x8 v; bf16 e[8]; } O;
#pragma unroll
        for (int j = 0; j < 8; ++j) O.e[j] = f2b(r[j]);
        *reinterpret_cast<bf16x8*>(out + i8) = O.v;
    } else {
#pragma unroll
        for (int j = 0; j < 8; ++j) out[i8 + j] = r[j];
    }
}

// ---------------------------------------------------------------------------
// Prep: u0 = bf16(x) + zero pad row; pack 8 f32 weights into bf16 MFMA
// B-fragment order; zero stats; zero pad row of u3.
// ---------------------------------------------------------------------------
#define PACK_TOTAL 139264
__global__ __launch_bounds__(256) void prep_kernel(
    const float* __restrict__ x,
    const float* W0, const float* W1, const float* W2, const float* W3,
    const float* W4, const float* W5, const float* W6, const float* W7,
    bf16* __restrict__ u0, bf16* __restrict__ bpack,
    float* __restrict__ stats, bf16* __restrict__ u3)
{
    const int gid = blockIdx.x * 256 + threadIdx.x;
    constexpr int NXE = (N_VOX + 1) * 16;
    if (gid < NXE) {
        u0[gid] = (gid < N_VOX * 16) ? f2b(x[gid]) : f2b(0.f);
        return;
    }
    int p = gid - NXE;
    if (p < PACK_TOTAL) {
        constexpr int cin[8]  = {16, 32, 16, 32, 32, 64, 32, 64};
        constexpr int cout[8] = {32, 32, 32, 32, 64, 64, 64, 64};
        constexpr int offs[9] = {0, 5120, 14336, 19456, 28672, 47104, 83968, 102400, 139264};
        const float* Ws[8] = {W0, W1, W2, W3, W4, W5, W6, W7};
        int w = 0;
        while (p >= offs[w + 1]) ++w;
        const int e = p - offs[w];
        const int CI = cin[w], CO = cout[w];
        const int NTl = CO / 16;
        const int j = e & 7;
        const int lane = (e >> 3) & 63;
        const int rest = e >> 9;
        const int c = rest % NTl;
        const int t = rest / NTl;
        const int ncol = c * 16 + (lane & 15);
        const int k = t * 32 + (lane >> 4) * 8 + j;
        float val = 0.f;
        if (k < 9 * CI) {
            const int nbq = k / CI;
            const int ci = k % CI;
            val = Ws[w][(nbq * CI + ci) * CO + ncol];
        }
        bpack[p] = f2b(val);
        return;
    }
    p -= PACK_TOTAL;
    if (p < 1024) { stats[p] = 0.f; return; }
    p -= 1024;
    if (p < 32) u3[N_VOX * 32 + p] = f2b(0.f);
}

extern "C" void kernel_launch(void* const* d_in, const int* in_sizes, int n_in,
                              void* d_out, int out_size, void* d_ws, size_t ws_size,
                              hipStream_t stream) {
    const float* x     = (const float*)d_in[0];
    const int* nbr133  = (const int*)d_in[1];
    const int* nbr313  = (const int*)d_in[2];
    const float* W_c1  = (const float*)d_in[3];
    const float* g0    = (const float*)d_in[4];
    const float* b0    = (const float*)d_in[5];
    const float* W_c12 = (const float*)d_in[6];
    const float* g02   = (const float*)d_in[7];
    const float* b02   = (const float*)d_in[8];
    const float* W_c2  = (const float*)d_in[9];
    const float* W_c3  = (const float*)d_in[10];
    const float* g2    = (const float*)d_in[11];
    const float* b2    = (const float*)d_in[12];
    const float* W_r1  = (const float*)d_in[13];
    const float* rg0   = (const float*)d_in[14];
    const float* rb0   = (const float*)d_in[15];
    const float* W_r12 = (const float*)d_in[16];
    const float* rg02  = (const float*)d_in[17];
    const float* rb02  = (const float*)d_in[18];
    const float* W_r2  = (const float*)d_in[19];
    const float* rg1   = (const float*)d_in[20];
    const float* rb1   = (const float*)d_in[21];
    const float* W_r3  = (const float*)d_in[22];
    const float* rg2   = (const float*)d_in[23];
    const float* rb2   = (const float*)d_in[24];

    // Workspace aliasing schedule identical to R3/R5/R6 (correctness-proven).
    char* ws = (char*)d_ws;
    size_t off = 0;
    auto alloc = [&](size_t bytes) -> char* {
        off = (off + 255) & ~(size_t)255;
        char* p = ws + off;
        off += bytes;
        return p;
    };
    const size_t NV = N_VOX;
    bf16* u0   = (bf16*)alloc((NV + 1) * 16 * 2);
    bf16* B1u3 = (bf16*)alloc((NV + 1) * 32 * 2);
    bf16* T4   = (bf16*)alloc(NV * 32 * 2);
    bf16* T2uy = (bf16*)alloc((NV + 1) * 32 * 2);
    bf16* B5B7 = (bf16*)alloc((NV + 1) * 64 * 2);
    bf16* T8   = (bf16*)alloc(NV * 64 * 2);
    bf16* bpack = (bf16*)alloc((size_t)PACK_TOTAL * 2);
    float* stats = (float*)alloc(1024 * 4);
    bf16* T6 = (bf16*)ws;    // alias R0..R2 (19.2 MB available >= 15.36 MB)

    float* st1 = stats + 0 * 128;
    float* st2 = stats + 1 * 128;
    float* st4 = stats + 3 * 128;
    float* st5 = stats + 4 * 128;
    float* st6 = stats + 5 * 128;
    float* st7 = stats + 6 * 128;
    float* st8 = stats + 7 * 128;

    bf16* bp0 = bpack + 0;       // W_c1  (16->32)
    bf16* bp1 = bpack + 5120;    // W_c12 (32->32)
    bf16* bp2 = bpack + 14336;   // W_c2  (16->32)
    bf16* bp3 = bpack + 19456;   // W_c3  (32->32)
    bf16* bp4 = bpack + 28672;   // W_r1  (32->64)
    bf16* bp5 = bpack + 47104;   // W_r12 (64->64)
    bf16* bp6 = bpack + 83968;   // W_r2  (32->64)
    bf16* bp7 = bpack + 102400;  // W_r3  (64->64)

    const int prep_total = (N_VOX + 1) * 16 + PACK_TOTAL + 1024 + 32;
    prep_kernel<<<(prep_total + 255) / 256, 256, 0, stream>>>(
        x, W_c1, W_c12, W_c2, W_c3, W_r1, W_r12, W_r2, W_r3, u0, bpack, stats, B1u3);

    const int E32 = (((N_VOX + 1) * 32) / 8 + 255) / 256;
    const int E64 = (((N_VOX + 1) * 64) / 8 + 255) / 256;

    // ResContextBlock
    conv_kernel<16, 32, 4, true><<<768, 256, 0, stream>>>(u0, nbr133, bp0, B1u3, st1);
    bnapply_kernel<32><<<E32, 256, 0, stream>>>(B1u3, st1, g0, b0);
    conv_kernel<32, 32, 4, true><<<768, 256, 0, stream>>>(B1u3, nbr313, bp1, T2uy, st2);
    conv_kernel<16, 32, 4, false><<<768, 256, 0, stream>>>(u0, nbr313, bp2, B1u3, nullptr);
    conv_kernel<32, 32, 4, true><<<768, 256, 0, stream>>>(B1u3, nbr133, bp3, T4, st4);
    addbn_kernel<32, true, bf16><<<E32, 256, 0, stream>>>(
        T2uy, st2, g02, b02, T4, st4, g2, b2, T2uy);
    // ResBlock
    conv_kernel<32, 64, 8, true><<<512, 512, 0, stream>>>(T2uy, nbr313, bp4, B5B7, st5);
    bnapply_kernel<64><<<E64, 256, 0, stream>>>(B5B7, st5, rg0, rb0);
    conv_kernel<64, 64, 16, true><<<256, 1024, 0, stream>>>(B5B7, nbr133, bp5, T6, st6);
    conv_kernel<32, 64, 8, true><<<512, 512, 0, stream>>>(T2uy, nbr133, bp6, B5B7, st7);
    bnapply_kernel<64><<<E64, 256, 0, stream>>>(B5B7, st7, rg1, rb1);
    conv_kernel<64, 64, 16, true><<<256, 1024, 0, stream>>>(B5B7, nbr313, bp7, T8, st8);
    addbn_kernel<64, false, float><<<((N_VOX * 64 / 8) + 255) / 256, 256, 0, stream>>>(
        T6, st6, rg02, rb02, T8, st8, rg2, rb2, (float*)d_out);
}

// Round 7
// 293.832 us; speedup vs baseline: 1.1272x; 1.1017x over previous
//
#include <hip/hip_runtime.h>
#include <hip/hip_bf16.h>

#define N_VOX 120000
#define NTILES (N_VOX / 16)   // 7500

typedef __attribute__((ext_vector_type(8))) __bf16 bf16x8;
typedef __attribute__((ext_vector_type(4))) float floatx4;
using bf16 = __hip_bfloat16;

__device__ __forceinline__ float b2f(bf16 v) { return __bfloat162float(v); }
__device__ __forceinline__ bf16 f2b(float v) { return __float2bfloat16(v); }

// All VMEM in the conv K-loop is inline asm: (a) compiler cannot sink/split
// the batched gathers, (b) vmcnt bookkeeping is deterministic, enabling
// cross-tile prefetch with exact s_waitcnt immediates.
__device__ __forceinline__ bf16x8 gload16(const bf16* p) {
    bf16x8 r;
    asm volatile("global_load_dwordx4 %0, %1, off" : "=v"(r) : "v"(p));
    return r;
}
__device__ __forceinline__ int gloadi(const int* p) {
    int r;
    asm volatile("global_load_dword %0, %1, off" : "=v"(r) : "v"(p));
    return r;
}
__device__ __forceinline__ void gstore16(bf16* p, bf16x8 v) {
    asm volatile("global_store_dwordx4 %0, %1, off" :: "v"(p), "v"(v) : "memory");
}
__device__ __forceinline__ void vm_wait0() { asm volatile("s_waitcnt vmcnt(0)" ::: "memory"); }
__device__ __forceinline__ void vm_wait1() { asm volatile("s_waitcnt vmcnt(1)" ::: "memory"); }
__device__ __forceinline__ void vm_wait2() { asm volatile("s_waitcnt vmcnt(2)" ::: "memory"); }
__device__ __forceinline__ void vm_wait3() { asm volatile("s_waitcnt vmcnt(3)" ::: "memory"); }
__device__ __forceinline__ void pin(bf16x8& x) { asm volatile("" : "+v"(x)); }
__device__ __forceinline__ void pini(int& x)   { asm volatile("" : "+v"(x)); }

// ---------------------------------------------------------------------------
// Gather-GEMM conv body (proven baseline choreography, UNCHANGED):
// one wave per 16-row tile, all COUT cols; grid-stride; no in-loop barriers;
// all gathers unconditional; idx loads coalesced via LDS (prefetched 1 tile
// ahead); C-tile transposed through wave-private LDS -> coalesced stores.
// R6: conv_body is shared by conv_kernel (single) and conv2_kernel (two
// INDEPENDENT same-shape convs in one dispatch, selected by blockIdx half —
// wave-uniform pointer select at entry only). STATS is a runtime pointer
// guard. Cuts 14 dispatches -> 10 and overlaps independent conv pairs.
// ---------------------------------------------------------------------------
template<int CIN, int COUT, int NW>
__device__ __forceinline__ void conv_body(
    const bf16* __restrict__ uin, const int* __restrict__ nbr,
    const bf16* __restrict__ bpack, bf16* __restrict__ tout,
    float* __restrict__ stats, int bid, int nblk)
{
    constexpr int NT = COUT / 16;
    constexpr int K = 9 * CIN;
    constexpr int KSTEPS = (K + 31) / 32;
    constexpr bool BLDS = (COUT == 64);
    constexpr int NFRAG = KSTEPS * NT;
    constexpr int NSTORE = (16 * COUT) / 512;   // 1 (COUT=32) or 2 (COUT=64)

    __shared__ bf16x8 Bs[BLDS ? NFRAG * 64 : 1];
    __shared__ int idxb[NW][2][192];
    __shared__ __align__(16) bf16 tbuf[NW][16 * COUT];
    __shared__ float sS[64], sS2[64];

    const int lane = threadIdx.x & 63;
    const int wave = threadIdx.x >> 6;
    const int m    = lane & 15;
    const int quad = lane >> 4;

    if (threadIdx.x < 64) { sS[threadIdx.x] = 0.f; sS2[threadIdx.x] = 0.f; }

    const bf16x8* bp = reinterpret_cast<const bf16x8*>(bpack);
    bf16x8 Bf[BLDS ? 1 : NFRAG];
    if constexpr (BLDS) {
        for (int f = threadIdx.x; f < NFRAG * 64; f += NW * 64) Bs[f] = bp[f];
    } else {
#pragma unroll
        for (int f = 0; f < NFRAG; ++f) Bf[f] = bp[f * 64 + lane];
    }
    __syncthreads();

    float ssum[NT], ssum2[NT];
#pragma unroll
    for (int c = 0; c < NT; ++c) { ssum[c] = 0.f; ssum2[c] = 0.f; }

    const int STRIDE = nblk * NW;
    const int t0 = bid * NW + wave;             // < NTILES by grid construction

    // Prologue: coalesced idx load for tile t0 (144 contiguous dwords).
    {
        const int* b0 = nbr + t0 * 144;
        int i0 = gloadi(b0 + lane);
        int i1 = gloadi(b0 + 64 + lane);
        int i2 = gloadi(b0 + 128 + (lane & 15));
        vm_wait0();
        pini(i0); pini(i1); pini(i2);
        int* ib = idxb[wave][0];
        ib[lane] = i0; ib[64 + lane] = i1; ib[128 + (lane & 15)] = i2;
    }

    int p = 0;
    for (int tile = t0; tile < NTILES; tile += STRIDE) {
        // 1) per-lane idx from LDS (no TA traffic)
        const int* ib = idxb[wave][p];
        int idx[9];
#pragma unroll
        for (int nb = 0; nb < 9; ++nb) idx[nb] = ib[m * 9 + nb];

        // 2) issue all K-panel gathers (asm, batched)
        bf16x8 a[KSTEPS];
#pragma unroll
        for (int t = 0; t < KSTEPS; ++t) {
            const bf16* src;
            if constexpr (CIN == 64) {
                src = uin + (((size_t)idx[t >> 1]) << 6) + ((t & 1) << 5) + quad * 8;
            } else if constexpr (CIN == 32) {
                src = uin + (((size_t)idx[t]) << 5) + quad * 8;
            } else {  // CIN == 16
                constexpr int KS = 9 * 16;
                const int j1 = (2 * t + 1 > 8) ? 8 : 2 * t + 1;
                int r_ = (quad & 2) ? idx[j1] : idx[2 * t];
                if (t * 32 + 24 >= KS) {
                    if (t * 32 + quad * 8 >= KS) r_ = N_VOX;  // tail -> pad row
                }
                src = uin + (((size_t)r_) << 4) + ((quad & 1) << 3);
            }
            a[t] = gload16(src);
        }

        // 3) prefetch next tile's idx (coalesced, stays in flight across MFMA)
        const int tnext = (tile + STRIDE < NTILES) ? tile + STRIDE : tile;
        const int* bn_ = nbr + tnext * 144;
        int i0 = gloadi(bn_ + lane);
        int i1 = gloadi(bn_ + 64 + lane);
        int i2 = gloadi(bn_ + 128 + (lane & 15));

        // 4) wait gathers (3 idx loads remain in flight), compute
        vm_wait3();
#pragma unroll
        for (int t = 0; t < KSTEPS; ++t) pin(a[t]);

        floatx4 acc[NT];
#pragma unroll
        for (int c = 0; c < NT; ++c) acc[c] = (floatx4){0.f, 0.f, 0.f, 0.f};
#pragma unroll
        for (int t = 0; t < KSTEPS; ++t) {
#pragma unroll
            for (int c = 0; c < NT; ++c) {
                const bf16x8 b = BLDS ? Bs[(t * NT + c) * 64 + lane] : Bf[t * NT + c];
                acc[c] = __builtin_amdgcn_mfma_f32_16x16x32_bf16(a[t], b, acc[c], 0, 0, 0);
            }
        }

        // 5) epilogue: lrelu + stats + LDS transpose + coalesced stores
        bf16* tb = tbuf[wave];
#pragma unroll
        for (int c = 0; c < NT; ++c) {
            float ps = 0.f, ps2 = 0.f;
#pragma unroll
            for (int i = 0; i < 4; ++i) {
                float v = acc[c][i];
                v = v > 0.f ? v : 0.01f * v;
                tb[(quad * 4 + i) * COUT + c * 16 + m] = f2b(v);
                ps += v; ps2 += v * v;
            }
            ssum[c] += ps; ssum2[c] += ps2;
        }
#pragma unroll
        for (int g = 0; g < NSTORE; ++g) {
            const int off = g * 512 + lane * 8;
            bf16x8 row = *reinterpret_cast<const bf16x8*>(tb + off);
            gstore16(tout + (size_t)tile * (16 * COUT) + off, row);
        }

        // 6) idx arrived (NSTORE stores still in flight); stash for next iter
        if constexpr (NSTORE == 2) vm_wait2(); else vm_wait1();
        pini(i0); pini(i1); pini(i2);
        int* ibn = idxb[wave][p ^ 1];
        ibn[lane] = i0; ibn[64 + lane] = i1; ibn[128 + (lane & 15)] = i2;
        p ^= 1;
    }

    if (stats != nullptr) {
#pragma unroll
        for (int c = 0; c < NT; ++c) {
            atomicAdd(&sS[c * 16 + m], ssum[c]);
            atomicAdd(&sS2[c * 16 + m], ssum2[c]);
        }
        __syncthreads();
        if (threadIdx.x < COUT) {
            atomicAdd(&stats[threadIdx.x],      sS[threadIdx.x]);
            atomicAdd(&stats[64 + threadIdx.x], sS2[threadIdx.x]);
        }
    }
}

template<int CIN, int COUT, int NW>
__global__ __launch_bounds__(NW * 64) void conv_kernel(
    const bf16* __restrict__ uin, const int* __restrict__ nbr,
    const bf16* __restrict__ bpack, bf16* __restrict__ tout,
    float* __restrict__ stats)
{
    conv_body<CIN, COUT, NW>(uin, nbr, bpack, tout, stats, blockIdx.x, gridDim.x);
}

// Two independent same-shape convs in one dispatch: blocks [0,GA) run conv A,
// [GA,2*GA) run conv B. Selection is wave-uniform (blockIdx), body unchanged.
template<int CIN, int COUT, int NW>
__global__ __launch_bounds__(NW * 64) void conv2_kernel(
    int GA,
    const bf16* uinA, const int* nbrA, const bf16* bpA, bf16* toutA, float* stA,
    const bf16* uinB, const int* nbrB, const bf16* bpB, bf16* toutB, float* stB)
{
    const bool isB = (int)blockIdx.x >= GA;
    const int bid = isB ? (int)blockIdx.x - GA : (int)blockIdx.x;
    const bf16* uin   = isB ? uinB : uinA;
    const int*  nbr   = isB ? nbrB : nbrA;
    const bf16* bpack = isB ? bpB  : bpA;
    bf16*       tout  = isB ? toutB : toutA;
    float*      stats = isB ? stB  : stA;
    conv_body<CIN, COUT, NW>(uin, nbr, bpack, tout, stats, bid, GA);
}

// ---------------------------------------------------------------------------
// In-place BN affine on t[N_VOX,C] (bf16) + zero pad row.
// ---------------------------------------------------------------------------
template<int C>
__device__ __forceinline__ void bnapply_body(
    bf16* t, const float* __restrict__ s,
    const float* __restrict__ g, const float* __restrict__ b, int bid)
{
    __shared__ float pa[64], pc[64];
    if (threadIdx.x < C) {
        const float inv_n = 1.0f / N_VOX;
        const float mu = s[threadIdx.x] * inv_n;
        const float var = fmaxf(s[64 + threadIdx.x] * inv_n - mu * mu, 0.f);
        const float a = rsqrtf(var + 1e-5f) * g[threadIdx.x];
        pa[threadIdx.x] = a;
        pc[threadIdx.x] = b[threadIdx.x] - mu * a;
    }
    __syncthreads();
    const int i8 = (bid * 256 + threadIdx.x) * 8;
    if (i8 >= (N_VOX + 1) * C) return;
    if (i8 >= N_VOX * C) {
        uint4 z = {0, 0, 0, 0};
        *reinterpret_cast<uint4*>(t + i8) = z;
        return;
    }
    union { bf16x8 v; bf16 e[8]; } U, O;
    U.v = *reinterpret_cast<const bf16x8*>(t + i8);
    const int ch0 = i8 & (C - 1);
#pragma unroll
    for (int j = 0; j < 8; ++j)
        O.e[j] = f2b(pa[ch0 + j] * b2f(U.e[j]) + pc[ch0 + j]);
    *reinterpret_cast<bf16x8*>(t + i8) = O.v;
}

template<int C>
__global__ __launch_bounds__(256) void bnapply_kernel(
    bf16* t, const float* __restrict__ s,
    const float* __restrict__ g, const float* __restrict__ b)
{
    bnapply_body<C>(t, s, g, b, blockIdx.x);
}

// Two independent 64-ch BN applies in one dispatch.
__global__ __launch_bounds__(256) void bnapply2_kernel(
    int GA, bf16* tA, const float* sA, const float* gA, const float* bA,
    bf16* tB, const float* sB, const float* gB, const float* bB)
{
    const bool isB = (int)blockIdx.x >= GA;
    const int bid = isB ? (int)blockIdx.x - GA : (int)blockIdx.x;
    bnapply_body<64>(isB ? tB : tA, isB ? sB : sA, isB ? gB : gA,
                     isB ? bB : bA, bid);
}

// ---------------------------------------------------------------------------
// out = BN_a(ta) + BN_b(tb); OUT bf16 (+pad row) or float (final).
// ---------------------------------------------------------------------------
template<int C, bool ZROW, typename OUT>
__global__ __launch_bounds__(256) void addbn_kernel(
    const bf16* ta, const float* __restrict__ sa,
    const float* __restrict__ ga, const float* __restrict__ ba,
    const bf16* tb, const float* __restrict__ sb,
    const float* __restrict__ gb, const float* __restrict__ bb,
    OUT* out)
{
    __shared__ float paa[64], pca[64], pab[64], pcb[64];
    if (threadIdx.x < C) {
        const float inv_n = 1.0f / N_VOX;
        const float ma = sa[threadIdx.x] * inv_n;
        const float va = fmaxf(sa[64 + threadIdx.x] * inv_n - ma * ma, 0.f);
        const float aa = rsqrtf(va + 1e-5f) * ga[threadIdx.x];
        paa[threadIdx.x] = aa;
        pca[threadIdx.x] = ba[threadIdx.x] - ma * aa;
        const float mb = sb[threadIdx.x] * inv_n;
        const float vb = fmaxf(sb[64 + threadIdx.x] * inv_n - mb * mb, 0.f);
        const float ab = rsqrtf(vb + 1e-5f) * gb[threadIdx.x];
        pab[threadIdx.x] = ab;
        pcb[threadIdx.x] = bb[threadIdx.x] - mb * ab;
    }
    __syncthreads();
    constexpr int TOTAL = (N_VOX + (ZROW ? 1 : 0)) * C;
    const int i8 = (blockIdx.x * 256 + threadIdx.x) * 8;
    if (i8 >= TOTAL) return;
    if (ZROW && i8 >= N_VOX * C) {
        uint4 z = {0, 0, 0, 0};
        *reinterpret_cast<uint4*>((bf16*)out + i8) = z;
        return;
    }
    union { bf16x8 v; bf16 e[8]; } A, B;
    A.v = *reinterpret_cast<const bf16x8*>(ta + i8);
    B.v = *reinterpret_cast<const bf16x8*>(tb + i8);
    const int ch0 = i8 & (C - 1);
    float r[8];
#pragma unroll
    for (int j = 0; j < 8; ++j)
        r[j] = paa[ch0 + j] * b2f(A.e[j]) + pca[ch0 + j]
             + pab[ch0 + j] * b2f(B.e[j]) + pcb[ch0 + j];
    if constexpr (sizeof(OUT) == 2) {
        union { bf16x8 v; bf16 e[8]; } O;
#pragma unroll
        for (int j = 0; j < 8; ++j) O.e[j] = f2b(r[j]);
        *reinterpret_cast<bf16x8*>(out + i8) = O.v;
    } else {
#pragma unroll
        for (int j = 0; j < 8; ++j) out[i8 + j] = r[j];
    }
}

// ---------------------------------------------------------------------------
// Prep: u0 = bf16(x) + zero pad row; pack 8 f32 weights into bf16 MFMA
// B-fragment order; zero stats; zero pad rows of u3 AND u3b (X3 buffer).
// ---------------------------------------------------------------------------
#define PACK_TOTAL 139264
__global__ __launch_bounds__(256) void prep_kernel(
    const float* __restrict__ x,
    const float* W0, const float* W1, const float* W2, const float* W3,
    const float* W4, const float* W5, const float* W6, const float* W7,
    bf16* __restrict__ u0, bf16* __restrict__ bpack,
    float* __restrict__ stats, bf16* __restrict__ u3, bf16* __restrict__ u3b)
{
    const int gid = blockIdx.x * 256 + threadIdx.x;
    constexpr int NXE = (N_VOX + 1) * 16;
    if (gid < NXE) {
        u0[gid] = (gid < N_VOX * 16) ? f2b(x[gid]) : f2b(0.f);
        return;
    }
    int p = gid - NXE;
    if (p < PACK_TOTAL) {
        constexpr int cin[8]  = {16, 32, 16, 32, 32, 64, 32, 64};
        constexpr int cout[8] = {32, 32, 32, 32, 64, 64, 64, 64};
        constexpr int offs[9] = {0, 5120, 14336, 19456, 28672, 47104, 83968, 102400, 139264};
        const float* Ws[8] = {W0, W1, W2, W3, W4, W5, W6, W7};
        int w = 0;
        while (p >= offs[w + 1]) ++w;
        const int e = p - offs[w];
        const int CI = cin[w], CO = cout[w];
        const int NTl = CO / 16;
        const int j = e & 7;
        const int lane = (e >> 3) & 63;
        const int rest = e >> 9;
        const int c = rest % NTl;
        const int t = rest / NTl;
        const int ncol = c * 16 + (lane & 15);
        const int k = t * 32 + (lane >> 4) * 8 + j;
        float val = 0.f;
        if (k < 9 * CI) {
            const int nbq = k / CI;
            const int ci = k % CI;
            val = Ws[w][(nbq * CI + ci) * CO + ncol];
        }
        bpack[p] = f2b(val);
        return;
    }
    p -= PACK_TOTAL;
    if (p < 1024) { stats[p] = 0.f; return; }
    p -= 1024;
    if (p < 32) { u3[N_VOX * 32 + p] = f2b(0.f); return; }
    p -= 32;
    if (p < 32) u3b[N_VOX * 32 + p] = f2b(0.f);
}

extern "C" void kernel_launch(void* const* d_in, const int* in_sizes, int n_in,
                              void* d_out, int out_size, void* d_ws, size_t ws_size,
                              hipStream_t stream) {
    const float* x     = (const float*)d_in[0];
    const int* nbr133  = (const int*)d_in[1];
    const int* nbr313  = (const int*)d_in[2];
    const float* W_c1  = (const float*)d_in[3];
    const float* g0    = (const float*)d_in[4];
    const float* b0    = (const float*)d_in[5];
    const float* W_c12 = (const float*)d_in[6];
    const float* g02   = (const float*)d_in[7];
    const float* b02   = (const float*)d_in[8];
    const float* W_c2  = (const float*)d_in[9];
    const float* W_c3  = (const float*)d_in[10];
    const float* g2    = (const float*)d_in[11];
    const float* b2    = (const float*)d_in[12];
    const float* W_r1  = (const float*)d_in[13];
    const float* rg0   = (const float*)d_in[14];
    const float* rb0   = (const float*)d_in[15];
    const float* W_r12 = (const float*)d_in[16];
    const float* rg02  = (const float*)d_in[17];
    const float* rb02  = (const float*)d_in[18];
    const float* W_r2  = (const float*)d_in[19];
    const float* rg1   = (const float*)d_in[20];
    const float* rb1   = (const float*)d_in[21];
    const float* W_r3  = (const float*)d_in[22];
    const float* rg2   = (const float*)d_in[23];
    const float* rb2   = (const float*)d_in[24];

    // Workspace layout identical to baseline; role re-plan for merged DAG:
    //  u0    [ 3.84MB] x bf16 (padded)
    //  B1u3  [ 7.68MB] X1 = C1 out -> bn1 in-place -> C2 input       (padded)
    //  T4    [ 7.68MB] X2 = C2 out (addbnY input, no pad needed)
    //  T2uy  [ 7.68MB] X3 = C3 out (padded, C4 input) -> Y = addbnY out (padded)
    //  B5B7  [15.36MB] X4 = C4 out (front half) -> Z1 = R1 out -> bn ->
    //                  M4a input -> Z4 = M4b out -> addbnOut input
    //  T8    [15.36MB] Z3 = R2r out -> bn -> M4b input
    //  T6=ws [15.36MB] Z2 = M4a out (aliases u0/B1u3/T4, all dead by then)
    char* ws = (char*)d_ws;
    size_t off = 0;
    auto alloc = [&](size_t bytes) -> char* {
        off = (off + 255) & ~(size_t)255;
        char* p = ws + off;
        off += bytes;
        return p;
    };
    const size_t NV = N_VOX;
    bf16* u0   = (bf16*)alloc((NV + 1) * 16 * 2);
    bf16* B1u3 = (bf16*)alloc((NV + 1) * 32 * 2);
    bf16* T4   = (bf16*)alloc(NV * 32 * 2);
    bf16* T2uy = (bf16*)alloc((NV + 1) * 32 * 2);
    bf16* B5B7 = (bf16*)alloc((NV + 1) * 64 * 2);
    bf16* T8   = (bf16*)alloc(NV * 64 * 2);
    bf16* bpack = (bf16*)alloc((size_t)PACK_TOTAL * 2);
    float* stats = (float*)alloc(1024 * 4);
    bf16* T6 = (bf16*)ws;    // alias u0..T4 (19.2 MB available >= 15.36 MB)

    float* st1 = stats + 0 * 128;
    float* st2 = stats + 1 * 128;
    float* st4 = stats + 3 * 128;
    float* st5 = stats + 4 * 128;
    float* st6 = stats + 5 * 128;
    float* st7 = stats + 6 * 128;
    float* st8 = stats + 7 * 128;

    bf16* bp0 = bpack + 0;       // W_c1  (16->32)
    bf16* bp1 = bpack + 5120;    // W_c12 (32->32)
    bf16* bp2 = bpack + 14336;   // W_c2  (16->32)
    bf16* bp3 = bpack + 19456;   // W_c3  (32->32)
    bf16* bp4 = bpack + 28672;   // W_r1  (32->64)
    bf16* bp5 = bpack + 47104;   // W_r12 (64->64)
    bf16* bp6 = bpack + 83968;   // W_r2  (32->64)
    bf16* bp7 = bpack + 102400;  // W_r3  (64->64)

    const int prep_total = (N_VOX + 1) * 16 + PACK_TOTAL + 1024 + 32 + 32;
    prep_kernel<<<(prep_total + 255) / 256, 256, 0, stream>>>(
        x, W_c1, W_c12, W_c2, W_c3, W_r1, W_r12, W_r2, W_r3,
        u0, bpack, stats, B1u3, T2uy);

    const int E32 = (((N_VOX + 1) * 32) / 8 + 255) / 256;
    const int E64 = (((N_VOX + 1) * 64) / 8 + 255) / 256;

    // ResContextBlock
    // M1: C1 (u0 --133--> X1:B1u3, st1)  ||  C3 (u0 --313--> X3:T2uy)
    conv2_kernel<16, 32, 4><<<1536, 256, 0, stream>>>(
        768, u0, nbr133, bp0, B1u3, st1, u0, nbr313, bp2, T2uy, nullptr);
    bnapply_kernel<32><<<E32, 256, 0, stream>>>(B1u3, st1, g0, b0);
    // M2: C2 (X1':B1u3 --313--> X2:T4, st2) || C4 (X3:T2uy --133--> X4:B5B7, st4)
    conv2_kernel<32, 32, 4><<<1536, 256, 0, stream>>>(
        768, B1u3, nbr313, bp1, T4, st2, T2uy, nbr133, bp3, B5B7, st4);
    // Y = BN(X2) + BN(X4) -> T2uy (padded)
    addbn_kernel<32, true, bf16><<<E32, 256, 0, stream>>>(
        T4, st2, g02, b02, B5B7, st4, g2, b2, T2uy);
    // ResBlock
    // M3: R1 (Y --313--> Z1:B5B7, st5) || R2r (Y --133--> Z3:T8, st7)
    conv2_kernel<32, 64, 8><<<1024, 512, 0, stream>>>(
        512, T2uy, nbr313, bp4, B5B7, st5, T2uy, nbr133, bp6, T8, st7);
    // BN(Z1) and BN(Z3) in one dispatch (+pad zero both)
    bnapply2_kernel<<<2 * E64, 256, 0, stream>>>(
        E64, B5B7, st5, rg0, rb0, T8, st7, rg1, rb1);
    // M4a: Z1' --133--> Z2:T6 ; M4b: Z3' --313--> Z4:B5B7 (Z1' dead)
    conv_kernel<64, 64, 8><<<256, 512, 0, stream>>>(B5B7, nbr133, bp5, T6, st6);
    conv_kernel<64, 64, 8><<<256, 512, 0, stream>>>(T8, nbr313, bp7, B5B7, st8);
    addbn_kernel<64, false, float><<<((N_VOX * 64 / 8) + 255) / 256, 256, 0, stream>>>(
        T6, st6, rg02, rb02, B5B7, st8, rg2, rb2, (float*)d_out);
}

// Round 10
// 269.702 us; speedup vs baseline: 1.2280x; 1.0895x over previous
//
#include <hip/hip_runtime.h>
#include <hip/hip_bf16.h>

#define N_VOX 120000
#define NTILES (N_VOX / 16)   // 7500

typedef __attribute__((ext_vector_type(8))) __bf16 bf16x8;
typedef __attribute__((ext_vector_type(4))) float floatx4;
using bf16 = __hip_bfloat16;

__device__ __forceinline__ float b2f(bf16 v) { return __bfloat162float(v); }
__device__ __forceinline__ bf16 f2b(float v) { return __float2bfloat16(v); }

// All VMEM in the conv K-loop is inline asm: (a) compiler cannot sink/split
// the batched gathers, (b) vmcnt bookkeeping is deterministic. NOTE (R7/R8
// lesson): asm-load destination registers must be consumed in a SHORT,
// straight-line window — holding an in-flight asm load across a loop
// iteration lets regalloc copy/reassign the destination before the load
// lands (=> NaN). Cross-tile register pipelining is structurally unsafe at
// HIP source level; the R6 body below is the proven choreography.
__device__ __forceinline__ bf16x8 gload16(const bf16* p) {
    bf16x8 r;
    asm volatile("global_load_dwordx4 %0, %1, off" : "=v"(r) : "v"(p));
    return r;
}
__device__ __forceinline__ int gloadi(const int* p) {
    int r;
    asm volatile("global_load_dword %0, %1, off" : "=v"(r) : "v"(p));
    return r;
}
__device__ __forceinline__ void gstore16(bf16* p, bf16x8 v) {
    asm volatile("global_store_dwordx4 %0, %1, off" :: "v"(p), "v"(v) : "memory");
}
__device__ __forceinline__ void vm_wait0() { asm volatile("s_waitcnt vmcnt(0)" ::: "memory"); }
__device__ __forceinline__ void vm_wait1() { asm volatile("s_waitcnt vmcnt(1)" ::: "memory"); }
__device__ __forceinline__ void vm_wait2() { asm volatile("s_waitcnt vmcnt(2)" ::: "memory"); }
__device__ __forceinline__ void vm_wait3() { asm volatile("s_waitcnt vmcnt(3)" ::: "memory"); }
__device__ __forceinline__ void pin(bf16x8& x) { asm volatile("" : "+v"(x)); }
__device__ __forceinline__ void pini(int& x)   { asm volatile("" : "+v"(x)); }

// ---------------------------------------------------------------------------
// Gather-GEMM conv body — PROVEN R6 choreography, unchanged.
// R9 changes are launch-level only: M3 grid halved (tiles/wave 0.9 -> 3.7,
// amortizes 36KB Bs-load + prologue, engages the idx prefetch), and M4a/M4b
// merged into one conv2 dispatch writing disjoint buffers.
// ---------------------------------------------------------------------------
template<int CIN, int COUT, int NW>
__device__ __forceinline__ void conv_body(
    const bf16* __restrict__ uin,     // [N_VOX+1, CIN], pad row zero
    const int*  __restrict__ nbr,     // [N_VOX, 9]
    const bf16* __restrict__ bpack,   // prepacked B frags
    bf16* __restrict__ tout,          // [N_VOX, COUT]
    float* __restrict__ stats, int bid, int nblk)
{
    constexpr int NT = COUT / 16;
    constexpr int K = 9 * CIN;
    constexpr int KSTEPS = (K + 31) / 32;
    constexpr bool BLDS = (COUT == 64);
    constexpr int NFRAG = KSTEPS * NT;
    constexpr int NSTORE = (16 * COUT) / 512;   // 1 (COUT=32) or 2 (COUT=64)

    __shared__ bf16x8 Bs[BLDS ? NFRAG * 64 : 1];
    __shared__ int idxb[NW][2][192];
    __shared__ __align__(16) bf16 tbuf[NW][16 * COUT];
    __shared__ float sS[64], sS2[64];

    const int lane = threadIdx.x & 63;
    const int wave = threadIdx.x >> 6;
    const int m    = lane & 15;
    const int quad = lane >> 4;

    if (threadIdx.x < 64) { sS[threadIdx.x] = 0.f; sS2[threadIdx.x] = 0.f; }

    const bf16x8* bp = reinterpret_cast<const bf16x8*>(bpack);
    bf16x8 Bf[BLDS ? 1 : NFRAG];
    if constexpr (BLDS) {
        for (int f = threadIdx.x; f < NFRAG * 64; f += NW * 64) Bs[f] = bp[f];
    } else {
#pragma unroll
        for (int f = 0; f < NFRAG; ++f) Bf[f] = bp[f * 64 + lane];
    }
    __syncthreads();

    float ssum[NT], ssum2[NT];
#pragma unroll
    for (int c = 0; c < NT; ++c) { ssum[c] = 0.f; ssum2[c] = 0.f; }

    const int STRIDE = nblk * NW;
    const int t0 = bid * NW + wave;             // < NTILES by grid construction

    // Prologue: coalesced idx load for tile t0 (144 contiguous dwords).
    {
        const int* b0 = nbr + (size_t)t0 * 144;
        int i0 = gloadi(b0 + lane);
        int i1 = gloadi(b0 + 64 + lane);
        int i2 = gloadi(b0 + 128 + (lane & 15));
        vm_wait0();
        pini(i0); pini(i1); pini(i2);
        int* ib = idxb[wave][0];
        ib[lane] = i0; ib[64 + lane] = i1; ib[128 + (lane & 15)] = i2;
    }

    int p = 0;
    for (int tile = t0; tile < NTILES; tile += STRIDE) {
        // 1) per-lane idx from LDS (no TA traffic)
        const int* ib = idxb[wave][p];
        int idx[9];
#pragma unroll
        for (int nb = 0; nb < 9; ++nb) idx[nb] = ib[m * 9 + nb];

        // 2) issue all K-panel gathers (asm, batched)
        bf16x8 a[KSTEPS];
#pragma unroll
        for (int t = 0; t < KSTEPS; ++t) {
            const bf16* src;
            if constexpr (CIN == 64) {
                src = uin + (((size_t)idx[t >> 1]) << 6) + ((t & 1) << 5) + quad * 8;
            } else if constexpr (CIN == 32) {
                src = uin + (((size_t)idx[t]) << 5) + quad * 8;
            } else {  // CIN == 16
                constexpr int KS = 9 * 16;
                const int j1 = (2 * t + 1 > 8) ? 8 : 2 * t + 1;
                int r_ = (quad & 2) ? idx[j1] : idx[2 * t];
                if (t * 32 + 24 >= KS) {
                    if (t * 32 + quad * 8 >= KS) r_ = N_VOX;  // tail -> pad row
                }
                src = uin + (((size_t)r_) << 4) + ((quad & 1) << 3);
            }
            a[t] = gload16(src);
        }

        // 3) prefetch next tile's idx (coalesced, stays in flight across MFMA)
        const int tnext = (tile + STRIDE < NTILES) ? tile + STRIDE : tile;
        const int* bn_ = nbr + (size_t)tnext * 144;
        int i0 = gloadi(bn_ + lane);
        int i1 = gloadi(bn_ + 64 + lane);
        int i2 = gloadi(bn_ + 128 + (lane & 15));

        // 4) wait gathers (3 idx loads remain in flight), compute
        vm_wait3();
#pragma unroll
        for (int t = 0; t < KSTEPS; ++t) pin(a[t]);

        floatx4 acc[NT];
#pragma unroll
        for (int c = 0; c < NT; ++c) acc[c] = (floatx4){0.f, 0.f, 0.f, 0.f};
#pragma unroll
        for (int t = 0; t < KSTEPS; ++t) {
#pragma unroll
            for (int c = 0; c < NT; ++c) {
                const bf16x8 b = BLDS ? Bs[(t * NT + c) * 64 + lane] : Bf[t * NT + c];
                acc[c] = __builtin_amdgcn_mfma_f32_16x16x32_bf16(a[t], b, acc[c], 0, 0, 0);
            }
        }

        // 5) epilogue: lrelu + stats + LDS transpose + coalesced stores
        bf16* tb = tbuf[wave];
#pragma unroll
        for (int c = 0; c < NT; ++c) {
            float ps = 0.f, ps2 = 0.f;
#pragma unroll
            for (int i = 0; i < 4; ++i) {
                float v = acc[c][i];
                v = v > 0.f ? v : 0.01f * v;
                tb[(quad * 4 + i) * COUT + c * 16 + m] = f2b(v);
                ps += v; ps2 += v * v;
            }
            ssum[c] += ps; ssum2[c] += ps2;
        }
#pragma unroll
        for (int g = 0; g < NSTORE; ++g) {
            const int off = g * 512 + lane * 8;
            bf16x8 row = *reinterpret_cast<const bf16x8*>(tb + off);
            gstore16(tout + (size_t)tile * (16 * COUT) + off, row);
        }

        // 6) idx arrived (NSTORE stores still in flight); stash for next iter
        if constexpr (NSTORE == 2) vm_wait2(); else vm_wait1();
        pini(i0); pini(i1); pini(i2);
        int* ibn = idxb[wave][p ^ 1];
        ibn[lane] = i0; ibn[64 + lane] = i1; ibn[128 + (lane & 15)] = i2;
        p ^= 1;
    }

    if (stats != nullptr) {
#pragma unroll
        for (int c = 0; c < NT; ++c) {
            atomicAdd(&sS[c * 16 + m], ssum[c]);
            atomicAdd(&sS2[c * 16 + m], ssum2[c]);
        }
        __syncthreads();
        if (threadIdx.x < COUT) {
            atomicAdd(&stats[threadIdx.x],      sS[threadIdx.x]);
            atomicAdd(&stats[64 + threadIdx.x], sS2[threadIdx.x]);
        }
    }
}

template<int CIN, int COUT, int NW>
__global__ __launch_bounds__(NW * 64) void conv_kernel(
    const bf16* __restrict__ uin, const int* __restrict__ nbr,
    const bf16* __restrict__ bpack, bf16* __restrict__ tout,
    float* __restrict__ stats)
{
    conv_body<CIN, COUT, NW>(uin, nbr, bpack, tout, stats, blockIdx.x, gridDim.x);
}

// Two independent same-shape convs in one dispatch: blocks [0,GA) run conv A,
// [GA,2*GA) run conv B. Selection is wave-uniform (blockIdx), body unchanged.
template<int CIN, int COUT, int NW>
__global__ __launch_bounds__(NW * 64) void conv2_kernel(
    int GA,
    const bf16* uinA, const int* nbrA, const bf16* bpA, bf16* toutA, float* stA,
    const bf16* uinB, const int* nbrB, const bf16* bpB, bf16* toutB, float* stB)
{
    const bool isB = (int)blockIdx.x >= GA;
    const int bid = isB ? (int)blockIdx.x - GA : (int)blockIdx.x;
    const bf16* uin   = isB ? uinB : uinA;
    const int*  nbr   = isB ? nbrB : nbrA;
    const bf16* bpack = isB ? bpB  : bpA;
    bf16*       tout  = isB ? toutB : toutA;
    float*      stats = isB ? stB  : stA;
    conv_body<CIN, COUT, NW>(uin, nbr, bpack, tout, stats, bid, GA);
}

// ---------------------------------------------------------------------------
// In-place BN affine on t[N_VOX,C] (bf16) + zero pad row.
// ---------------------------------------------------------------------------
template<int C>
__device__ __forceinline__ void bnapply_body(
    bf16* t, const float* __restrict__ s,
    const float* __restrict__ g, const float* __restrict__ b, int bid)
{
    __shared__ float pa[64], pc[64];
    if (threadIdx.x < C) {
        const float inv_n = 1.0f / N_VOX;
        const float mu = s[threadIdx.x] * inv_n;
        const float var = fmaxf(s[64 + threadIdx.x] * inv_n - mu * mu, 0.f);
        const float a = rsqrtf(var + 1e-5f) * g[threadIdx.x];
        pa[threadIdx.x] = a;
        pc[threadIdx.x] = b[threadIdx.x] - mu * a;
    }
    __syncthreads();
    const int i8 = (bid * 256 + threadIdx.x) * 8;
    if (i8 >= (N_VOX + 1) * C) return;
    if (i8 >= N_VOX * C) {
        uint4 z = {0, 0, 0, 0};
        *reinterpret_cast<uint4*>(t + i8) = z;
        return;
    }
    union { bf16x8 v; bf16 e[8]; } U, O;
    U.v = *reinterpret_cast<const bf16x8*>(t + i8);
    const int ch0 = i8 & (C - 1);
#pragma unroll
    for (int j = 0; j < 8; ++j)
        O.e[j] = f2b(pa[ch0 + j] * b2f(U.e[j]) + pc[ch0 + j]);
    *reinterpret_cast<bf16x8*>(t + i8) = O.v;
}

template<int C>
__global__ __launch_bounds__(256) void bnapply_kernel(
    bf16* t, const float* __restrict__ s,
    const float* __restrict__ g, const float* __restrict__ b)
{
    bnapply_body<C>(t, s, g, b, blockIdx.x);
}

// Two independent 64-ch BN applies in one dispatch.
__global__ __launch_bounds__(256) void bnapply2_kernel(
    int GA, bf16* tA, const float* sA, const float* gA, const float* bA,
    bf16* tB, const float* sB, const float* gB, const float* bB)
{
    const bool isB = (int)blockIdx.x >= GA;
    const int bid = isB ? (int)blockIdx.x - GA : (int)blockIdx.x;
    bnapply_body<64>(isB ? tB : tA, isB ? sB : sA, isB ? gB : gA,
                     isB ? bB : bA, bid);
}

// ---------------------------------------------------------------------------
// out = BN_a(ta) + BN_b(tb); OUT bf16 (+pad row) or float (final).
// ---------------------------------------------------------------------------
template<int C, bool ZROW, typename OUT>
__global__ __launch_bounds__(256) void addbn_kernel(
    const bf16* ta, const float* __restrict__ sa,
    const float* __restrict__ ga, const float* __restrict__ ba,
    const bf16* tb, const float* __restrict__ sb,
    const float* __restrict__ gb, const float* __restrict__ bb,
    OUT* out)
{
    __shared__ float paa[64], pca[64], pab[64], pcb[64];
    if (threadIdx.x < C) {
        const float inv_n = 1.0f / N_VOX;
        const float ma = sa[threadIdx.x] * inv_n;
        const float va = fmaxf(sa[64 + threadIdx.x] * inv_n - ma * ma, 0.f);
        const float aa = rsqrtf(va + 1e-5f) * ga[threadIdx.x];
        paa[threadIdx.x] = aa;
        pca[threadIdx.x] = ba[threadIdx.x] - ma * aa;
        const float mb = sb[threadIdx.x] * inv_n;
        const float vb = fmaxf(sb[64 + threadIdx.x] * inv_n - mb * mb, 0.f);
        const float ab = rsqrtf(vb + 1e-5f) * gb[threadIdx.x];
        pab[threadIdx.x] = ab;
        pcb[threadIdx.x] = bb[threadIdx.x] - mb * ab;
    }
    __syncthreads();
    constexpr int TOTAL = (N_VOX + (ZROW ? 1 : 0)) * C;
    const int i8 = (blockIdx.x * 256 + threadIdx.x) * 8;
    if (i8 >= TOTAL) return;
    if (ZROW && i8 >= N_VOX * C) {
        uint4 z = {0, 0, 0, 0};
        *reinterpret_cast<uint4*>((bf16*)out + i8) = z;
        return;
    }
    union { bf16x8 v; bf16 e[8]; } A, B;
    A.v = *reinterpret_cast<const bf16x8*>(ta + i8);
    B.v = *reinterpret_cast<const bf16x8*>(tb + i8);
    const int ch0 = i8 & (C - 1);
    float r[8];
#pragma unroll
    for (int j = 0; j < 8; ++j)
        r[j] = paa[ch0 + j] * b2f(A.e[j]) + pca[ch0 + j]
             + pab[ch0 + j] * b2f(B.e[j]) + pcb[ch0 + j];
    if constexpr (sizeof(OUT) == 2) {
        union { bf16x8 v; bf16 e[8]; } O;
#pragma unroll
        for (int j = 0; j < 8; ++j) O.e[j] = f2b(r[j]);
        *reinterpret_cast<bf16x8*>(out + i8) = O.v;
    } else {
#pragma unroll
        for (int j = 0; j < 8; ++j) out[i8 + j] = r[j];
    }
}

// ---------------------------------------------------------------------------
// Prep: u0 = bf16(x) + zero pad row; pack 8 f32 weights into bf16 MFMA
// B-fragment order; zero stats; zero pad rows of u3 AND u3b (X3 buffer).
// ---------------------------------------------------------------------------
#define PACK_TOTAL 139264
__global__ __launch_bounds__(256) void prep_kernel(
    const float* __restrict__ x,
    const float* W0, const float* W1, const float* W2, const float* W3,
    const float* W4, const float* W5, const float* W6, const float* W7,
    bf16* __restrict__ u0, bf16* __restrict__ bpack,
    float* __restrict__ stats, bf16* __restrict__ u3, bf16* __restrict__ u3b)
{
    const int gid = blockIdx.x * 256 + threadIdx.x;
    constexpr int NXE = (N_VOX + 1) * 16;
    if (gid < NXE) {
        u0[gid] = (gid < N_VOX * 16) ? f2b(x[gid]) : f2b(0.f);
        return;
    }
    int p = gid - NXE;
    if (p < PACK_TOTAL) {
        constexpr int cin[8]  = {16, 32, 16, 32, 32, 64, 32, 64};
        constexpr int cout[8] = {32, 32, 32, 32, 64, 64, 64, 64};
        constexpr int offs[9] = {0, 5120, 14336, 19456, 28672, 47104, 83968, 102400, 139264};
        const float* Ws[8] = {W0, W1, W2, W3, W4, W5, W6, W7};
        int w = 0;
        while (p >= offs[w + 1]) ++w;
        const int e = p - offs[w];
        const int CI = cin[w], CO = cout[w];
        const int NTl = CO / 16;
        const int j = e & 7;
        const int lane = (e >> 3) & 63;
        const int rest = e >> 9;
        const int c = rest % NTl;
        const int t = rest / NTl;
        const int ncol = c * 16 + (lane & 15);
        const int k = t * 32 + (lane >> 4) * 8 + j;
        float val = 0.f;
        if (k < 9 * CI) {
            const int nbq = k / CI;
            const int ci = k % CI;
            val = Ws[w][(nbq * CI + ci) * CO + ncol];
        }
        bpack[p] = f2b(val);
        return;
    }
    p -= PACK_TOTAL;
    if (p < 1024) { stats[p] = 0.f; return; }
    p -= 1024;
    if (p < 32) { u3[N_VOX * 32 + p] = f2b(0.f); return; }
    p -= 32;
    if (p < 32) u3b[N_VOX * 32 + p] = f2b(0.f);
}

extern "C" void kernel_launch(void* const* d_in, const int* in_sizes, int n_in,
                              void* d_out, int out_size, void* d_ws, size_t ws_size,
                              hipStream_t stream) {
    const float* x     = (const float*)d_in[0];
    const int* nbr133  = (const int*)d_in[1];
    const int* nbr313  = (const int*)d_in[2];
    const float* W_c1  = (const float*)d_in[3];
    const float* g0    = (const float*)d_in[4];
    const float* b0    = (const float*)d_in[5];
    const float* W_c12 = (const float*)d_in[6];
    const float* g02   = (const float*)d_in[7];
    const float* b02   = (const float*)d_in[8];
    const float* W_c2  = (const float*)d_in[9];
    const float* W_c3  = (const float*)d_in[10];
    const float* g2    = (const float*)d_in[11];
    const float* b2    = (const float*)d_in[12];
    const float* W_r1  = (const float*)d_in[13];
    const float* rg0   = (const float*)d_in[14];
    const float* rb0   = (const float*)d_in[15];
    const float* W_r12 = (const float*)d_in[16];
    const float* rg02  = (const float*)d_in[17];
    const float* rb02  = (const float*)d_in[18];
    const float* W_r2  = (const float*)d_in[19];
    const float* rg1   = (const float*)d_in[20];
    const float* rb1   = (const float*)d_in[21];
    const float* W_r3  = (const float*)d_in[22];
    const float* rg2   = (const float*)d_in[23];
    const float* rb2   = (const float*)d_in[24];

    // Workspace layout = R6 + new T9 (M4b output, breaks the M4a/M4b WAR
    // dependency so both run in one conv2 dispatch). Harness poisons ~268MB
    // of workspace, so the extra 15.36MB is well within ws_size.
    char* ws = (char*)d_ws;
    size_t off = 0;
    auto alloc = [&](size_t bytes) -> char* {
        off = (off + 255) & ~(size_t)255;
        char* p = ws + off;
        off += bytes;
        return p;
    };
    const size_t NV = N_VOX;
    bf16* u0   = (bf16*)alloc((NV + 1) * 16 * 2);
    bf16* B1u3 = (bf16*)alloc((NV + 1) * 32 * 2);
    bf16* T4   = (bf16*)alloc(NV * 32 * 2);
    bf16* T2uy = (bf16*)alloc((NV + 1) * 32 * 2);
    bf16* B5B7 = (bf16*)alloc((NV + 1) * 64 * 2);
    bf16* T8   = (bf16*)alloc(NV * 64 * 2);
    bf16* bpack = (bf16*)alloc((size_t)PACK_TOTAL * 2);
    float* stats = (float*)alloc(1024 * 4);
    bf16* T9   = (bf16*)alloc(NV * 64 * 2);   // M4b out (Z4)
    bf16* T6 = (bf16*)ws;    // alias u0..T4 (19.2 MB available >= 15.36 MB)

    float* st1 = stats + 0 * 128;
    float* st2 = stats + 1 * 128;
    float* st4 = stats + 3 * 128;
    float* st5 = stats + 4 * 128;
    float* st6 = stats + 5 * 128;
    float* st7 = stats + 6 * 128;
    float* st8 = stats + 7 * 128;

    bf16* bp0 = bpack + 0;       // W_c1  (16->32)
    bf16* bp1 = bpack + 5120;    // W_c12 (32->32)
    bf16* bp2 = bpack + 14336;   // W_c2  (16->32)
    bf16* bp3 = bpack + 19456;   // W_c3  (32->32)
    bf16* bp4 = bpack + 28672;   // W_r1  (32->64)
    bf16* bp5 = bpack + 47104;   // W_r12 (64->64)
    bf16* bp6 = bpack + 83968;   // W_r2  (32->64)
    bf16* bp7 = bpack + 102400;  // W_r3  (64->64)

    const int prep_total = (N_VOX + 1) * 16 + PACK_TOTAL + 1024 + 32 + 32;
    prep_kernel<<<(prep_total + 255) / 256, 256, 0, stream>>>(
        x, W_c1, W_c12, W_c2, W_c3, W_r1, W_r12, W_r2, W_r3,
        u0, bpack, stats, B1u3, T2uy);

    const int E32 = (((N_VOX + 1) * 32) / 8 + 255) / 256;
    const int E64 = (((N_VOX + 1) * 64) / 8 + 255) / 256;

    // ResContextBlock
    // M1: C1 (u0 --133--> X1:B1u3, st1)  ||  C3 (u0 --313--> X3:T2uy)
    conv2_kernel<16, 32, 4><<<1536, 256, 0, stream>>>(
        768, u0, nbr133, bp0, B1u3, st1, u0, nbr313, bp2, T2uy, nullptr);
    bnapply_kernel<32><<<E32, 256, 0, stream>>>(B1u3, st1, g0, b0);
    // M2: C2 (X1':B1u3 --313--> X2:T4, st2) || C4 (X3:T2uy --133--> X4:B5B7, st4)
    conv2_kernel<32, 32, 4><<<1536, 256, 0, stream>>>(
        768, B1u3, nbr313, bp1, T4, st2, T2uy, nbr133, bp3, B5B7, st4);
    // Y = BN(X2) + BN(X4) -> T2uy (padded)
    addbn_kernel<32, true, bf16><<<E32, 256, 0, stream>>>(
        T4, st2, g02, b02, B5B7, st4, g2, b2, T2uy);
    // ResBlock
    // M3: R1 (Y --313--> Z1:B5B7, st5) || R2r (Y --133--> Z3:T8, st7)
    // GA=256: 512 blocks = 2 blocks/CU exactly resident (64.5KB LDS);
    // tiles/wave 0.92 -> 3.7, amortizing the 36KB Bs-load + prologue.
    conv2_kernel<32, 64, 8><<<512, 512, 0, stream>>>(
        256, T2uy, nbr313, bp4, B5B7, st5, T2uy, nbr133, bp6, T8, st7);
    // BN(Z1) and BN(Z3) in one dispatch (+pad zero both)
    bnapply2_kernel<<<2 * E64, 256, 0, stream>>>(
        E64, B5B7, st5, rg0, rb0, T8, st7, rg1, rb1);
    // M4: Z1' --133--> Z2:T6  ||  Z3' --313--> Z4:T9  (disjoint in/out)
    conv2_kernel<64, 64, 8><<<512, 512, 0, stream>>>(
        256, B5B7, nbr133, bp5, T6, st6, T8, nbr313, bp7, T9, st8);
    addbn_kernel<64, false, float><<<((N_VOX * 64 / 8) + 255) / 256, 256, 0, stream>>>(
        T6, st6, rg02, rb02, T9, st8, rg2, rb2, (float*)d_out);
}

// Round 11
// 258.705 us; speedup vs baseline: 1.2802x; 1.0425x over previous
//
#include <hip/hip_runtime.h>
#include <hip/hip_bf16.h>

#define N_VOX 120000
#define NTILES (N_VOX / 16)   // 7500

typedef __attribute__((ext_vector_type(8))) __bf16 bf16x8;
typedef __attribute__((ext_vector_type(4))) float floatx4;
using bf16 = __hip_bfloat16;

__device__ __forceinline__ float b2f(bf16 v) { return __bfloat162float(v); }
__device__ __forceinline__ bf16 f2b(float v) { return __float2bfloat16(v); }

// All VMEM in the conv K-loop is inline asm: (a) compiler cannot sink/split
// the batched gathers, (b) vmcnt bookkeeping is deterministic. NOTE (R7/R8
// lesson): asm-load destination registers must be consumed in a SHORT,
// straight-line window — holding an in-flight asm load across a loop
// iteration lets regalloc copy/reassign the destination before the load
// lands (=> NaN). Cross-tile register pipelining is structurally unsafe at
// HIP source level; the R6 body below is the proven choreography.
__device__ __forceinline__ bf16x8 gload16(const bf16* p) {
    bf16x8 r;
    asm volatile("global_load_dwordx4 %0, %1, off" : "=v"(r) : "v"(p));
    return r;
}
__device__ __forceinline__ int gloadi(const int* p) {
    int r;
    asm volatile("global_load_dword %0, %1, off" : "=v"(r) : "v"(p));
    return r;
}
__device__ __forceinline__ void gstore16(bf16* p, bf16x8 v) {
    asm volatile("global_store_dwordx4 %0, %1, off" :: "v"(p), "v"(v) : "memory");
}
__device__ __forceinline__ void vm_wait0() { asm volatile("s_waitcnt vmcnt(0)" ::: "memory"); }
__device__ __forceinline__ void vm_wait1() { asm volatile("s_waitcnt vmcnt(1)" ::: "memory"); }
__device__ __forceinline__ void vm_wait2() { asm volatile("s_waitcnt vmcnt(2)" ::: "memory"); }
__device__ __forceinline__ void vm_wait3() { asm volatile("s_waitcnt vmcnt(3)" ::: "memory"); }
__device__ __forceinline__ void pin(bf16x8& x) { asm volatile("" : "+v"(x)); }
__device__ __forceinline__ void pini(int& x)   { asm volatile("" : "+v"(x)); }

// ---------------------------------------------------------------------------
// Gather-GEMM conv body — PROVEN R6 choreography, unchanged.
// R10 change is launch-level only: M4 conv2<64,64> runs NW=16 (1024 thr).
// Bs (72KB) is per-block, so bigger blocks amortize it: LDS 129KB still
// 1 block/CU, but 16 waves/CU = 4 waves/SIMD — 2x TLP for gather-latency
// hiding on the heaviest dispatch (48us, MfmaUtil 13%, all pipes idle).
// VGPR=88 <= 128 sustains 4 waves/SIMD. M3 stays NW=8 (already 16 waves/CU
// via 2 blocks/CU).
// ---------------------------------------------------------------------------
template<int CIN, int COUT, int NW>
__device__ __forceinline__ void conv_body(
    const bf16* __restrict__ uin,     // [N_VOX+1, CIN], pad row zero
    const int*  __restrict__ nbr,     // [N_VOX, 9]
    const bf16* __restrict__ bpack,   // prepacked B frags
    bf16* __restrict__ tout,          // [N_VOX, COUT]
    float* __restrict__ stats, int bid, int nblk)
{
    constexpr int NT = COUT / 16;
    constexpr int K = 9 * CIN;
    constexpr int KSTEPS = (K + 31) / 32;
    constexpr bool BLDS = (COUT == 64);
    constexpr int NFRAG = KSTEPS * NT;
    constexpr int NSTORE = (16 * COUT) / 512;   // 1 (COUT=32) or 2 (COUT=64)

    __shared__ bf16x8 Bs[BLDS ? NFRAG * 64 : 1];
    __shared__ int idxb[NW][2][192];
    __shared__ __align__(16) bf16 tbuf[NW][16 * COUT];
    __shared__ float sS[64], sS2[64];

    const int lane = threadIdx.x & 63;
    const int wave = threadIdx.x >> 6;
    const int m    = lane & 15;
    const int quad = lane >> 4;

    if (threadIdx.x < 64) { sS[threadIdx.x] = 0.f; sS2[threadIdx.x] = 0.f; }

    const bf16x8* bp = reinterpret_cast<const bf16x8*>(bpack);
    bf16x8 Bf[BLDS ? 1 : NFRAG];
    if constexpr (BLDS) {
        for (int f = threadIdx.x; f < NFRAG * 64; f += NW * 64) Bs[f] = bp[f];
    } else {
#pragma unroll
        for (int f = 0; f < NFRAG; ++f) Bf[f] = bp[f * 64 + lane];
    }
    __syncthreads();

    float ssum[NT], ssum2[NT];
#pragma unroll
    for (int c = 0; c < NT; ++c) { ssum[c] = 0.f; ssum2[c] = 0.f; }

    const int STRIDE = nblk * NW;
    const int t0 = bid * NW + wave;             // < NTILES by grid construction

    // Prologue: coalesced idx load for tile t0 (144 contiguous dwords).
    {
        const int* b0 = nbr + (size_t)t0 * 144;
        int i0 = gloadi(b0 + lane);
        int i1 = gloadi(b0 + 64 + lane);
        int i2 = gloadi(b0 + 128 + (lane & 15));
        vm_wait0();
        pini(i0); pini(i1); pini(i2);
        int* ib = idxb[wave][0];
        ib[lane] = i0; ib[64 + lane] = i1; ib[128 + (lane & 15)] = i2;
    }

    int p = 0;
    for (int tile = t0; tile < NTILES; tile += STRIDE) {
        // 1) per-lane idx from LDS (no TA traffic)
        const int* ib = idxb[wave][p];
        int idx[9];
#pragma unroll
        for (int nb = 0; nb < 9; ++nb) idx[nb] = ib[m * 9 + nb];

        // 2) issue all K-panel gathers (asm, batched)
        bf16x8 a[KSTEPS];
#pragma unroll
        for (int t = 0; t < KSTEPS; ++t) {
            const bf16* src;
            if constexpr (CIN == 64) {
                src = uin + (((size_t)idx[t >> 1]) << 6) + ((t & 1) << 5) + quad * 8;
            } else if constexpr (CIN == 32) {
                src = uin + (((size_t)idx[t]) << 5) + quad * 8;
            } else {  // CIN == 16
                constexpr int KS = 9 * 16;
                const int j1 = (2 * t + 1 > 8) ? 8 : 2 * t + 1;
                int r_ = (quad & 2) ? idx[j1] : idx[2 * t];
                if (t * 32 + 24 >= KS) {
                    if (t * 32 + quad * 8 >= KS) r_ = N_VOX;  // tail -> pad row
                }
                src = uin + (((size_t)r_) << 4) + ((quad & 1) << 3);
            }
            a[t] = gload16(src);
        }

        // 3) prefetch next tile's idx (coalesced, stays in flight across MFMA)
        const int tnext = (tile + STRIDE < NTILES) ? tile + STRIDE : tile;
        const int* bn_ = nbr + (size_t)tnext * 144;
        int i0 = gloadi(bn_ + lane);
        int i1 = gloadi(bn_ + 64 + lane);
        int i2 = gloadi(bn_ + 128 + (lane & 15));

        // 4) wait gathers (3 idx loads remain in flight), compute
        vm_wait3();
#pragma unroll
        for (int t = 0; t < KSTEPS; ++t) pin(a[t]);

        floatx4 acc[NT];
#pragma unroll
        for (int c = 0; c < NT; ++c) acc[c] = (floatx4){0.f, 0.f, 0.f, 0.f};
#pragma unroll
        for (int t = 0; t < KSTEPS; ++t) {
#pragma unroll
            for (int c = 0; c < NT; ++c) {
                const bf16x8 b = BLDS ? Bs[(t * NT + c) * 64 + lane] : Bf[t * NT + c];
                acc[c] = __builtin_amdgcn_mfma_f32_16x16x32_bf16(a[t], b, acc[c], 0, 0, 0);
            }
        }

        // 5) epilogue: lrelu + stats + LDS transpose + coalesced stores
        bf16* tb = tbuf[wave];
#pragma unroll
        for (int c = 0; c < NT; ++c) {
            float ps = 0.f, ps2 = 0.f;
#pragma unroll
            for (int i = 0; i < 4; ++i) {
                float v = acc[c][i];
                v = v > 0.f ? v : 0.01f * v;
                tb[(quad * 4 + i) * COUT + c * 16 + m] = f2b(v);
                ps += v; ps2 += v * v;
            }
            ssum[c] += ps; ssum2[c] += ps2;
        }
#pragma unroll
        for (int g = 0; g < NSTORE; ++g) {
            const int off = g * 512 + lane * 8;
            bf16x8 row = *reinterpret_cast<const bf16x8*>(tb + off);
            gstore16(tout + (size_t)tile * (16 * COUT) + off, row);
        }

        // 6) idx arrived (NSTORE stores still in flight); stash for next iter
        if constexpr (NSTORE == 2) vm_wait2(); else vm_wait1();
        pini(i0); pini(i1); pini(i2);
        int* ibn = idxb[wave][p ^ 1];
        ibn[lane] = i0; ibn[64 + lane] = i1; ibn[128 + (lane & 15)] = i2;
        p ^= 1;
    }

    if (stats != nullptr) {
#pragma unroll
        for (int c = 0; c < NT; ++c) {
            atomicAdd(&sS[c * 16 + m], ssum[c]);
            atomicAdd(&sS2[c * 16 + m], ssum2[c]);
        }
        __syncthreads();
        if (threadIdx.x < COUT) {
            atomicAdd(&stats[threadIdx.x],      sS[threadIdx.x]);
            atomicAdd(&stats[64 + threadIdx.x], sS2[threadIdx.x]);
        }
    }
}

template<int CIN, int COUT, int NW>
__global__ __launch_bounds__(NW * 64) void conv_kernel(
    const bf16* __restrict__ uin, const int* __restrict__ nbr,
    const bf16* __restrict__ bpack, bf16* __restrict__ tout,
    float* __restrict__ stats)
{
    conv_body<CIN, COUT, NW>(uin, nbr, bpack, tout, stats, blockIdx.x, gridDim.x);
}

// Two independent same-shape convs in one dispatch: blocks [0,GA) run conv A,
// [GA,2*GA) run conv B. Selection is wave-uniform (blockIdx), body unchanged.
template<int CIN, int COUT, int NW>
__global__ __launch_bounds__(NW * 64) void conv2_kernel(
    int GA,
    const bf16* uinA, const int* nbrA, const bf16* bpA, bf16* toutA, float* stA,
    const bf16* uinB, const int* nbrB, const bf16* bpB, bf16* toutB, float* stB)
{
    const bool isB = (int)blockIdx.x >= GA;
    const int bid = isB ? (int)blockIdx.x - GA : (int)blockIdx.x;
    const bf16* uin   = isB ? uinB : uinA;
    const int*  nbr   = isB ? nbrB : nbrA;
    const bf16* bpack = isB ? bpB  : bpA;
    bf16*       tout  = isB ? toutB : toutA;
    float*      stats = isB ? stB  : stA;
    conv_body<CIN, COUT, NW>(uin, nbr, bpack, tout, stats, bid, GA);
}

// ---------------------------------------------------------------------------
// In-place BN affine on t[N_VOX,C] (bf16) + zero pad row.
// ---------------------------------------------------------------------------
template<int C>
__device__ __forceinline__ void bnapply_body(
    bf16* t, const float* __restrict__ s,
    const float* __restrict__ g, const float* __restrict__ b, int bid)
{
    __shared__ float pa[64], pc[64];
    if (threadIdx.x < C) {
        const float inv_n = 1.0f / N_VOX;
        const float mu = s[threadIdx.x] * inv_n;
        const float var = fmaxf(s[64 + threadIdx.x] * inv_n - mu * mu, 0.f);
        const float a = rsqrtf(var + 1e-5f) * g[threadIdx.x];
        pa[threadIdx.x] = a;
        pc[threadIdx.x] = b[threadIdx.x] - mu * a;
    }
    __syncthreads();
    const int i8 = (bid * 256 + threadIdx.x) * 8;
    if (i8 >= (N_VOX + 1) * C) return;
    if (i8 >= N_VOX * C) {
        uint4 z = {0, 0, 0, 0};
        *reinterpret_cast<uint4*>(t + i8) = z;
        return;
    }
    union { bf16x8 v; bf16 e[8]; } U, O;
    U.v = *reinterpret_cast<const bf16x8*>(t + i8);
    const int ch0 = i8 & (C - 1);
#pragma unroll
    for (int j = 0; j < 8; ++j)
        O.e[j] = f2b(pa[ch0 + j] * b2f(U.e[j]) + pc[ch0 + j]);
    *reinterpret_cast<bf16x8*>(t + i8) = O.v;
}

template<int C>
__global__ __launch_bounds__(256) void bnapply_kernel(
    bf16* t, const float* __restrict__ s,
    const float* __restrict__ g, const float* __restrict__ b)
{
    bnapply_body<C>(t, s, g, b, blockIdx.x);
}

// Two independent 64-ch BN applies in one dispatch.
__global__ __launch_bounds__(256) void bnapply2_kernel(
    int GA, bf16* tA, const float* sA, const float* gA, const float* bA,
    bf16* tB, const float* sB, const float* gB, const float* bB)
{
    const bool isB = (int)blockIdx.x >= GA;
    const int bid = isB ? (int)blockIdx.x - GA : (int)blockIdx.x;
    bnapply_body<64>(isB ? tB : tA, isB ? sB : sA, isB ? gB : gA,
                     isB ? bB : bA, bid);
}

// ---------------------------------------------------------------------------
// out = BN_a(ta) + BN_b(tb); OUT bf16 (+pad row) or float (final).
// ---------------------------------------------------------------------------
template<int C, bool ZROW, typename OUT>
__global__ __launch_bounds__(256) void addbn_kernel(
    const bf16* ta, const float* __restrict__ sa,
    const float* __restrict__ ga, const float* __restrict__ ba,
    const bf16* tb, const float* __restrict__ sb,
    const float* __restrict__ gb, const float* __restrict__ bb,
    OUT* out)
{
    __shared__ float paa[64], pca[64], pab[64], pcb[64];
    if (threadIdx.x < C) {
        const float inv_n = 1.0f / N_VOX;
        const float ma = sa[threadIdx.x] * inv_n;
        const float va = fmaxf(sa[64 + threadIdx.x] * inv_n - ma * ma, 0.f);
        const float aa = rsqrtf(va + 1e-5f) * ga[threadIdx.x];
        paa[threadIdx.x] = aa;
        pca[threadIdx.x] = ba[threadIdx.x] - ma * aa;
        const float mb = sb[threadIdx.x] * inv_n;
        const float vb = fmaxf(sb[64 + threadIdx.x] * inv_n - mb * mb, 0.f);
        const float ab = rsqrtf(vb + 1e-5f) * gb[threadIdx.x];
        pab[threadIdx.x] = ab;
        pcb[threadIdx.x] = bb[threadIdx.x] - mb * ab;
    }
    __syncthreads();
    constexpr int TOTAL = (N_VOX + (ZROW ? 1 : 0)) * C;
    const int i8 = (blockIdx.x * 256 + threadIdx.x) * 8;
    if (i8 >= TOTAL) return;
    if (ZROW && i8 >= N_VOX * C) {
        uint4 z = {0, 0, 0, 0};
        *reinterpret_cast<uint4*>((bf16*)out + i8) = z;
        return;
    }
    union { bf16x8 v; bf16 e[8]; } A, B;
    A.v = *reinterpret_cast<const bf16x8*>(ta + i8);
    B.v = *reinterpret_cast<const bf16x8*>(tb + i8);
    const int ch0 = i8 & (C - 1);
    float r[8];
#pragma unroll
    for (int j = 0; j < 8; ++j)
        r[j] = paa[ch0 + j] * b2f(A.e[j]) + pca[ch0 + j]
             + pab[ch0 + j] * b2f(B.e[j]) + pcb[ch0 + j];
    if constexpr (sizeof(OUT) == 2) {
        union { bf16x8 v; bf16 e[8]; } O;
#pragma unroll
        for (int j = 0; j < 8; ++j) O.e[j] = f2b(r[j]);
        *reinterpret_cast<bf16x8*>(out + i8) = O.v;
    } else {
#pragma unroll
        for (int j = 0; j < 8; ++j) out[i8 + j] = r[j];
    }
}

// ---------------------------------------------------------------------------
// Prep: u0 = bf16(x) + zero pad row; pack 8 f32 weights into bf16 MFMA
// B-fragment order; zero stats; zero pad rows of u3 AND u3b (X3 buffer).
// ---------------------------------------------------------------------------
#define PACK_TOTAL 139264
__global__ __launch_bounds__(256) void prep_kernel(
    const float* __restrict__ x,
    const float* W0, const float* W1, const float* W2, const float* W3,
    const float* W4, const float* W5, const float* W6, const float* W7,
    bf16* __restrict__ u0, bf16* __restrict__ bpack,
    float* __restrict__ stats, bf16* __restrict__ u3, bf16* __restrict__ u3b)
{
    const int gid = blockIdx.x * 256 + threadIdx.x;
    constexpr int NXE = (N_VOX + 1) * 16;
    if (gid < NXE) {
        u0[gid] = (gid < N_VOX * 16) ? f2b(x[gid]) : f2b(0.f);
        return;
    }
    int p = gid - NXE;
    if (p < PACK_TOTAL) {
        constexpr int cin[8]  = {16, 32, 16, 32, 32, 64, 32, 64};
        constexpr int cout[8] = {32, 32, 32, 32, 64, 64, 64, 64};
        constexpr int offs[9] = {0, 5120, 14336, 19456, 28672, 47104, 83968, 102400, 139264};
        const float* Ws[8] = {W0, W1, W2, W3, W4, W5, W6, W7};
        int w = 0;
        while (p >= offs[w + 1]) ++w;
        const int e = p - offs[w];
        const int CI = cin[w], CO = cout[w];
        const int NTl = CO / 16;
        const int j = e & 7;
        const int lane = (e >> 3) & 63;
        const int rest = e >> 9;
        const int c = rest % NTl;
        const int t = rest / NTl;
        const int ncol = c * 16 + (lane & 15);
        const int k = t * 32 + (lane >> 4) * 8 + j;
        float val = 0.f;
        if (k < 9 * CI) {
            const int nbq = k / CI;
            const int ci = k % CI;
            val = Ws[w][(nbq * CI + ci) * CO + ncol];
        }
        bpack[p] = f2b(val);
        return;
    }
    p -= PACK_TOTAL;
    if (p < 1024) { stats[p] = 0.f; return; }
    p -= 1024;
    if (p < 32) { u3[N_VOX * 32 + p] = f2b(0.f); return; }
    p -= 32;
    if (p < 32) u3b[N_VOX * 32 + p] = f2b(0.f);
}

extern "C" void kernel_launch(void* const* d_in, const int* in_sizes, int n_in,
                              void* d_out, int out_size, void* d_ws, size_t ws_size,
                              hipStream_t stream) {
    const float* x     = (const float*)d_in[0];
    const int* nbr133  = (const int*)d_in[1];
    const int* nbr313  = (const int*)d_in[2];
    const float* W_c1  = (const float*)d_in[3];
    const float* g0    = (const float*)d_in[4];
    const float* b0    = (const float*)d_in[5];
    const float* W_c12 = (const float*)d_in[6];
    const float* g02   = (const float*)d_in[7];
    const float* b02   = (const float*)d_in[8];
    const float* W_c2  = (const float*)d_in[9];
    const float* W_c3  = (const float*)d_in[10];
    const float* g2    = (const float*)d_in[11];
    const float* b2    = (const float*)d_in[12];
    const float* W_r1  = (const float*)d_in[13];
    const float* rg0   = (const float*)d_in[14];
    const float* rb0   = (const float*)d_in[15];
    const float* W_r12 = (const float*)d_in[16];
    const float* rg02  = (const float*)d_in[17];
    const float* rb02  = (const float*)d_in[18];
    const float* W_r2  = (const float*)d_in[19];
    const float* rg1   = (const float*)d_in[20];
    const float* rb1   = (const float*)d_in[21];
    const float* W_r3  = (const float*)d_in[22];
    const float* rg2   = (const float*)d_in[23];
    const float* rb2   = (const float*)d_in[24];

    // Workspace layout = R9 (correctness-proven).
    char* ws = (char*)d_ws;
    size_t off = 0;
    auto alloc = [&](size_t bytes) -> char* {
        off = (off + 255) & ~(size_t)255;
        char* p = ws + off;
        off += bytes;
        return p;
    };
    const size_t NV = N_VOX;
    bf16* u0   = (bf16*)alloc((NV + 1) * 16 * 2);
    bf16* B1u3 = (bf16*)alloc((NV + 1) * 32 * 2);
    bf16* T4   = (bf16*)alloc(NV * 32 * 2);
    bf16* T2uy = (bf16*)alloc((NV + 1) * 32 * 2);
    bf16* B5B7 = (bf16*)alloc((NV + 1) * 64 * 2);
    bf16* T8   = (bf16*)alloc(NV * 64 * 2);
    bf16* bpack = (bf16*)alloc((size_t)PACK_TOTAL * 2);
    float* stats = (float*)alloc(1024 * 4);
    bf16* T9   = (bf16*)alloc(NV * 64 * 2);   // M4b out (Z4)
    bf16* T6 = (bf16*)ws;    // alias u0..T4 (19.2 MB available >= 15.36 MB)

    float* st1 = stats + 0 * 128;
    float* st2 = stats + 1 * 128;
    float* st4 = stats + 3 * 128;
    float* st5 = stats + 4 * 128;
    float* st6 = stats + 5 * 128;
    float* st7 = stats + 6 * 128;
    float* st8 = stats + 7 * 128;

    bf16* bp0 = bpack + 0;       // W_c1  (16->32)
    bf16* bp1 = bpack + 5120;    // W_c12 (32->32)
    bf16* bp2 = bpack + 14336;   // W_c2  (16->32)
    bf16* bp3 = bpack + 19456;   // W_c3  (32->32)
    bf16* bp4 = bpack + 28672;   // W_r1  (32->64)
    bf16* bp5 = bpack + 47104;   // W_r12 (64->64)
    bf16* bp6 = bpack + 83968;   // W_r2  (32->64)
    bf16* bp7 = bpack + 102400;  // W_r3  (64->64)

    const int prep_total = (N_VOX + 1) * 16 + PACK_TOTAL + 1024 + 32 + 32;
    prep_kernel<<<(prep_total + 255) / 256, 256, 0, stream>>>(
        x, W_c1, W_c12, W_c2, W_c3, W_r1, W_r12, W_r2, W_r3,
        u0, bpack, stats, B1u3, T2uy);

    const int E32 = (((N_VOX + 1) * 32) / 8 + 255) / 256;
    const int E64 = (((N_VOX + 1) * 64) / 8 + 255) / 256;

    // ResContextBlock
    // M1: C1 (u0 --133--> X1:B1u3, st1)  ||  C3 (u0 --313--> X3:T2uy)
    conv2_kernel<16, 32, 4><<<1536, 256, 0, stream>>>(
        768, u0, nbr133, bp0, B1u3, st1, u0, nbr313, bp2, T2uy, nullptr);
    bnapply_kernel<32><<<E32, 256, 0, stream>>>(B1u3, st1, g0, b0);
    // M2: C2 (X1':B1u3 --313--> X2:T4, st2) || C4 (X3:T2uy --133--> X4:B5B7, st4)
    conv2_kernel<32, 32, 4><<<1536, 256, 0, stream>>>(
        768, B1u3, nbr313, bp1, T4, st2, T2uy, nbr133, bp3, B5B7, st4);
    // Y = BN(X2) + BN(X4) -> T2uy (padded)
    addbn_kernel<32, true, bf16><<<E32, 256, 0, stream>>>(
        T4, st2, g02, b02, B5B7, st4, g2, b2, T2uy);
    // ResBlock
    // M3: R1 (Y --313--> Z1:B5B7, st5) || R2r (Y --133--> Z3:T8, st7)
    // GA=256: 512 blocks = 2 blocks/CU exactly resident (64.5KB LDS);
    // tiles/wave 3.7, amortizing the 36KB Bs-load + prologue.
    conv2_kernel<32, 64, 8><<<512, 512, 0, stream>>>(
        256, T2uy, nbr313, bp4, B5B7, st5, T2uy, nbr133, bp6, T8, st7);
    // BN(Z1) and BN(Z3) in one dispatch (+pad zero both)
    bnapply2_kernel<<<2 * E64, 256, 0, stream>>>(
        E64, B5B7, st5, rg0, rb0, T8, st7, rg1, rb1);
    // M4: Z1' --133--> Z2:T6  ||  Z3' --313--> Z4:T9  (disjoint in/out)
    // NW=16: LDS 129KB -> still 1 block/CU, but 16 waves/CU (4/SIMD) = 2x TLP.
    conv2_kernel<64, 64, 16><<<256, 1024, 0, stream>>>(
        128, B5B7, nbr133, bp5, T6, st6, T8, nbr313, bp7, T9, st8);
    addbn_kernel<64, false, float><<<((N_VOX * 64 / 8) + 255) / 256, 256, 0, stream>>>(
        T6, st6, rg02, rb02, T9, st8, rg2, rb2, (float*)d_out);
}